// Round 9
// baseline (179.168 us; speedup 1.0000x reference)
//
#include <hip/hip_runtime.h>
#include <hip/hip_bf16.h>

#define Bb 2
#define Tt 2048
#define Cc 1024
#define Hh 16
#define HD 64
// 1/sqrt(64) * log2(e), folded into q at QKV epilogue so attn exp2 needs no mul
#define QS 0.18033688f

typedef __attribute__((ext_vector_type(8))) short bf16x8;
typedef __attribute__((ext_vector_type(4))) short bf16x4;
typedef __attribute__((ext_vector_type(4))) float f32x4;
typedef __attribute__((ext_vector_type(2))) unsigned int u32x2;

__device__ inline short f2b(float f) {
    unsigned int u = __builtin_bit_cast(unsigned int, f);
    unsigned int r = (u + 0x7FFFu + ((u >> 16) & 1u)) >> 16;
    return (short)(unsigned short)r;
}

// async global->LDS, 16B per lane; dst must be wave-uniform base + lane*16
__device__ inline void gl16(const void* g, void* l) {
    __builtin_amdgcn_global_load_lds(
        (const __attribute__((address_space(1))) void*)g,
        (__attribute__((address_space(3))) void*)l, 16, 0, 0);
}

// ---------------------------------------------------------------------------
// Fused pre-pass (single launch):
//   blocks [0,2048):      x fp32 -> bf16
//   blocks [2048,2816):   w_attn [1024,3072] -> wAT [3072][1024] bf16
//   blocks [2816,3072):   w_proj [1024,1024] -> wPT [1024][1024] bf16
// ---------------------------------------------------------------------------
__global__ __launch_bounds__(256) void prep_kernel(
    const float* __restrict__ x, short* __restrict__ xbf,
    const float* __restrict__ wA, short* __restrict__ wAT,
    const float* __restrict__ wP, short* __restrict__ wPT)
{
    const int bx = blockIdx.x, tid = threadIdx.x;
    if (bx < 2048) {
        int i = (bx * 256 + tid) * 8;
        float4 a = *(const float4*)(x + i);
        float4 b = *(const float4*)(x + i + 4);
        bf16x8 v;
        v[0] = f2b(a.x); v[1] = f2b(a.y); v[2] = f2b(a.z); v[3] = f2b(a.w);
        v[4] = f2b(b.x); v[5] = f2b(b.y); v[6] = f2b(b.z); v[7] = f2b(b.w);
        *(bf16x8*)(xbf + i) = v;
        return;
    }
    const float* W; short* WT; int N, t;
    if (bx < 2816) { t = bx - 2048; W = wA; WT = wAT; N = 3072; }
    else           { t = bx - 2816; W = wP; WT = wPT; N = 1024; }
    const int K = 1024;
    int k0 = (t & 15) * 64, n0 = (t >> 4) * 64;
    int nl = tid & 63, kg = tid >> 6;
    int n = n0 + nl;
    short v[16];
#pragma unroll
    for (int i = 0; i < 16; i++)
        v[i] = f2b(W[(size_t)(k0 + kg * 16 + i) * N + n]);
    short* dst = WT + (size_t)n * K + k0 + kg * 16;
    *(bf16x8*)dst = *(bf16x8*)&v[0];
    *(bf16x8*)(dst + 8) = *(bf16x8*)&v[8];
}

#define VM0 asm volatile("s_waitcnt vmcnt(0)" ::: "memory")
#define BARRIER asm volatile("s_barrier" ::: "memory")
#define SCHEDB __builtin_amdgcn_sched_barrier(0)

// ---------------------------------------------------------------------------
// QKV GEMM v6 (round-5/6 winner): 128x128, BK=64, 4 waves, 64 KiB LDS ->
// 2 blocks/CU, grid 768, ONE vmcnt(0)+barrier per K-tile, Gray unique-read,
// XOR-swizzled staging.
// ---------------------------------------------------------------------------
#define STG(nb, kb) { \
    gl16(A + baA0 + (kb), &LB[((nb) << 1) * 4096 + dst8]); \
    gl16(A + baA0 + 32768 + (kb), &LB[((nb) << 1) * 4096 + 2048 + dst8]); \
    gl16(A + baA1 + (kb), &LB[(((nb) << 1) | 1) * 4096 + dst8]); \
    gl16(A + baA1 + 32768 + (kb), &LB[(((nb) << 1) | 1) * 4096 + 2048 + dst8]); \
    gl16(Bt + baB0 + (kb), &LB[16384 + ((nb) << 1) * 4096 + dst8]); \
    gl16(Bt + baB0 + 32768 + (kb), &LB[16384 + ((nb) << 1) * 4096 + 2048 + dst8]); \
    gl16(Bt + baB1 + (kb), &LB[16384 + (((nb) << 1) | 1) * 4096 + dst8]); \
    gl16(Bt + baB1 + 32768 + (kb), &LB[16384 + (((nb) << 1) | 1) * 4096 + 2048 + dst8]); }

#define RD_A(bb, flo) { \
    const short* Ab_ = &LB[(((bb) << 1) | wm) * 4096]; \
    _Pragma("unroll") for (int f_ = 0; f_ < 2; f_++) \
        _Pragma("unroll") for (int kh_ = 0; kh_ < 2; kh_++) \
            af[(flo) + f_][kh_] = *(const bf16x8*)&Ab_[aro[(flo) + f_] + kx[kh_]]; }

#define RD_B(bb, elo) { \
    const short* Bb_ = &LB[16384 + (((bb) << 1) | wn) * 4096]; \
    _Pragma("unroll") for (int e_ = 0; e_ < 2; e_++) \
        _Pragma("unroll") for (int kh_ = 0; kh_ < 2; kh_++) \
            bf[(elo) + e_][kh_] = *(const bf16x8*)&Bb_[bro[(elo) + e_] + kx[kh_]]; }

#define QMM(FH, EH) { \
    __builtin_amdgcn_s_setprio(1); \
    _Pragma("unroll") for (int f_ = 0; f_ < 2; f_++) \
        _Pragma("unroll") for (int e_ = 0; e_ < 2; e_++) \
            _Pragma("unroll") for (int kh_ = 0; kh_ < 2; kh_++) \
                acc[(FH) * 2 + f_][(EH) * 2 + e_] = \
                    __builtin_amdgcn_mfma_f32_16x16x32_bf16( \
                        af[(FH) * 2 + f_][kh_], bf[(EH) * 2 + e_][kh_], \
                        acc[(FH) * 2 + f_][(EH) * 2 + e_], 0, 0, 0); \
    __builtin_amdgcn_s_setprio(0); }

// one K-tile on buffer bb, staging (kb1) into nb; 1 vmcnt + 1 barrier total
#define TILE(bb, nb, kb1) { \
    RD_A(bb, 0); RD_B(bb, 0); \
    STG(nb, kb1); \
    QMM(0, 0); \
    RD_B(bb, 2); QMM(0, 1); \
    RD_A(bb, 2); QMM(1, 1); \
    QMM(1, 0); \
    VM0; BARRIER; SCHEDB; }

#define TILE_LAST(bb) { \
    RD_A(bb, 0); RD_B(bb, 0); \
    QMM(0, 0); \
    RD_B(bb, 2); QMM(0, 1); \
    RD_A(bb, 2); QMM(1, 1); \
    QMM(1, 0); }

__global__ __launch_bounds__(256, 2) void gemm_qkv(
    const short* __restrict__ A, const short* __restrict__ Bt,
    const float* __restrict__ bias,
    short* __restrict__ qw, short* __restrict__ kw, short* __restrict__ vTw,
    int M, int N, int K)
{
    __shared__ __attribute__((aligned(16))) short LB[32768]; // 64 KiB

    const int tid  = threadIdx.x;
    const int wave = tid >> 6, lane = tid & 63;
    const int quad = lane >> 4, lr = lane & 15;
    const int wm = wave >> 1, wn = wave & 1;

    const int bid = blockIdx.x;
    const int sw = (bid & 7) * 96 + (bid >> 3);   // XCD-chunked, bijective (768=8*96)
    const int bx = sw % 24, by = sw / 24;
    const int m0 = by * 128, n0 = bx * 128;

    const int dst8 = tid * 8;
    const int cs = ((tid & 7) ^ ((tid >> 3) & 7)) << 3;
    const size_t baA0 = (size_t)(m0 + (tid >> 3)) * 1024 + cs;
    const size_t baA1 = (size_t)(m0 + 64 + (tid >> 3)) * 1024 + cs;
    const size_t baB0 = (size_t)(n0 + (tid >> 3)) * 1024 + cs;
    const size_t baB1 = (size_t)(n0 + 64 + (tid >> 3)) * 1024 + cs;

    int aro[4], bro[4], kx[2];
#pragma unroll
    for (int f = 0; f < 4; f++) {
        aro[f] = (f * 16 + lr) * 64;
        bro[f] = (f * 16 + lr) * 64;
    }
#pragma unroll
    for (int kh = 0; kh < 2; kh++)
        kx[kh] = (((kh * 4 + quad) ^ (lr & 7)) << 3);

    f32x4 acc[4][4];
    const f32x4 zf = {0.f, 0.f, 0.f, 0.f};
#pragma unroll
    for (int mf = 0; mf < 4; mf++)
#pragma unroll
        for (int nf = 0; nf < 4; nf++) acc[mf][nf] = zf;

    bf16x8 af[4][2], bf[4][2];

    STG(0, 0);
    VM0;
    BARRIER;

    for (int it = 0; it < 7; ++it) {
        TILE(0, 1, (2 * it + 1) << 6);
        TILE(1, 0, (2 * it + 2) << 6);
    }
    TILE(0, 1, 15 << 6);   // tile 14, stages tile 15 -> buf 1
    TILE_LAST(1);          // tile 15

    if (n0 < 2048) {
#pragma unroll
        for (int nf = 0; nf < 4; nf++) {
#pragma unroll
            for (int mf = 0; mf < 4; mf++) {
                int c = n0 + wn * 64 + nf * 16 + lr;
                float bv = bias[c];
#pragma unroll
                for (int r = 0; r < 4; r++) {
                    int rg = m0 + wm * 64 + mf * 16 + quad * 4 + r;
                    float val = acc[mf][nf][r] + bv;
                    int which = c >> 10, cc = c & 1023;
                    int h = cc >> 6, d = cc & 63;
                    int b = rg >> 11, t = rg & 2047;
                    size_t bh = (size_t)b * Hh + h;
                    if (which == 0) qw[(bh * Tt + t) * HD + d] = f2b(val * QS);
                    else            kw[(bh * Tt + t) * HD + d] = f2b(val);
                }
            }
        }
    } else {
        __syncthreads();
#pragma unroll
        for (int nf = 0; nf < 4; nf++) {
            int cl = wn * 64 + nf * 16 + lr;
            float bv = bias[n0 + cl];
#pragma unroll
            for (int mf = 0; mf < 4; mf++)
#pragma unroll
                for (int r = 0; r < 4; r++) {
                    int tl = wm * 64 + mf * 16 + quad * 4 + r;
                    LB[cl * 136 + tl] = f2b(acc[mf][nf][r] + bv);
                }
        }
        __syncthreads();
        const int rl = tid >> 1, half = tid & 1;
        const int cc = (n0 & 1023) + rl;
        const int h = cc >> 6, d = cc & 63;
        const int b = m0 >> 11, tb = (m0 & 2047) + half * 64;
        short* dst = vTw + (((size_t)b * Hh + h) * HD + d) * Tt + tb;
        const short* src = &LB[rl * 136 + half * 64];
#pragma unroll
        for (int jj = 0; jj < 8; jj++)
            *(bf16x8*)(dst + jj * 8) = *(const bf16x8*)(src + jj * 8);
    }
}

// ---------------------------------------------------------------------------
// Proj GEMM v2 (unchanged): 64x128 tile, BK=64, 4 waves, 48 KiB LDS,
// 2 blocks/CU, ONE vmcnt(0)+barrier per K-tile, unique Gray reads.
// ---------------------------------------------------------------------------
#define P_STG(nb, kb) { \
    gl16(A + baA0 + (size_t)(kb) * 2048, &LB[(nb) * 4096 + dst8]); \
    gl16(A + baA1 + (size_t)(kb) * 2048, &LB[(nb) * 4096 + 2048 + dst8]); \
    gl16(Bt + baB0 + (kb), &LB[8192 + (nb) * 8192 + dst8]); \
    gl16(Bt + baB1 + (kb), &LB[8192 + (nb) * 8192 + 2048 + dst8]); \
    gl16(Bt + baB2 + (kb), &LB[8192 + (nb) * 8192 + 4096 + dst8]); \
    gl16(Bt + baB3 + (kb), &LB[8192 + (nb) * 8192 + 6144 + dst8]); }

#define P_RDA(bb) { \
    const short* Ab_ = &LB[(bb) * 4096]; \
    _Pragma("unroll") for (int f_ = 0; f_ < 2; f_++) \
        _Pragma("unroll") for (int kh_ = 0; kh_ < 2; kh_++) \
            af[f_][kh_] = *(const bf16x8*)&Ab_[aro[f_] + kx[kh_]]; }

#define P_RDB(bb, elo) { \
    const short* Bb_ = &LB[8192 + (bb) * 8192]; \
    _Pragma("unroll") for (int e_ = 0; e_ < 2; e_++) \
        _Pragma("unroll") for (int kh_ = 0; kh_ < 2; kh_++) \
            bf[(elo) + e_][kh_] = *(const bf16x8*)&Bb_[bro[(elo) + e_] + kx[kh_]]; }

#define P_QMM(EH) { \
    __builtin_amdgcn_s_setprio(1); \
    _Pragma("unroll") for (int f_ = 0; f_ < 2; f_++) \
        _Pragma("unroll") for (int e_ = 0; e_ < 2; e_++) \
            _Pragma("unroll") for (int kh_ = 0; kh_ < 2; kh_++) \
                acc[f_][(EH) * 2 + e_] = \
                    __builtin_amdgcn_mfma_f32_16x16x32_bf16( \
                        af[f_][kh_], bf[(EH) * 2 + e_][kh_], \
                        acc[f_][(EH) * 2 + e_], 0, 0, 0); \
    __builtin_amdgcn_s_setprio(0); }

#define P_TILE(bb, nb, kb1) { \
    P_RDA(bb); P_RDB(bb, 0); \
    P_STG(nb, kb1); \
    P_QMM(0); \
    P_RDB(bb, 2); P_QMM(1); \
    VM0; BARRIER; SCHEDB; }

#define P_TILE_LAST(bb) { \
    P_RDA(bb); P_RDB(bb, 0); \
    P_QMM(0); \
    P_RDB(bb, 2); P_QMM(1); }

__global__ __launch_bounds__(256, 2) void gemm_proj(
    const short* __restrict__ A, const short* __restrict__ Bt,
    const float* __restrict__ bias, float* __restrict__ out,
    int M, int N, int K)
{
    __shared__ __attribute__((aligned(16))) short LB[24576]; // 48 KiB

    const int tid  = threadIdx.x;
    const int wave = tid >> 6, lane = tid & 63;
    const int quad = lane >> 4, lr = lane & 15;
    const int wm = wave >> 1, wn = wave & 1;
    const int m0 = blockIdx.y * 64, n0 = blockIdx.x * 128;

    const int dst8 = tid * 8;
    const int cs = ((tid & 7) ^ ((tid >> 3) & 7)) << 3;
    size_t baA0, baA1;
    {
        int r0 = m0 + (tid >> 3), r1 = m0 + 32 + (tid >> 3);
        baA0 = (((size_t)(r0 >> 11) * Hh) * Tt + (r0 & 2047)) * HD + cs;
        baA1 = (((size_t)(r1 >> 11) * Hh) * Tt + (r1 & 2047)) * HD + cs;
    }
    const size_t baB0 = (size_t)(n0 + (tid >> 3)) * 1024 + cs;
    const size_t baB1 = (size_t)(n0 + 32 + (tid >> 3)) * 1024 + cs;
    const size_t baB2 = (size_t)(n0 + 64 + (tid >> 3)) * 1024 + cs;
    const size_t baB3 = (size_t)(n0 + 96 + (tid >> 3)) * 1024 + cs;

    int aro[2], bro[4], kx[2];
#pragma unroll
    for (int f = 0; f < 2; f++) aro[f] = (wm * 32 + f * 16 + lr) * 64;
#pragma unroll
    for (int e = 0; e < 4; e++) bro[e] = (wn * 64 + e * 16 + lr) * 64;
#pragma unroll
    for (int kh = 0; kh < 2; kh++)
        kx[kh] = (((kh * 4 + quad) ^ (lr & 7)) << 3);

    f32x4 acc[2][4];
    const f32x4 zf = {0.f, 0.f, 0.f, 0.f};
#pragma unroll
    for (int mi = 0; mi < 2; mi++)
#pragma unroll
        for (int ni = 0; ni < 4; ni++) acc[mi][ni] = zf;

    bf16x8 af[2][2], bf[4][2];

    P_STG(0, 0);
    VM0;
    BARRIER;

    for (int it = 0; it < 7; ++it) {
        P_TILE(0, 1, (2 * it + 1) << 6);
        P_TILE(1, 0, (2 * it + 2) << 6);
    }
    P_TILE(0, 1, 15 << 6);
    P_TILE_LAST(1);

#pragma unroll
    for (int mi = 0; mi < 2; mi++)
#pragma unroll
        for (int ni = 0; ni < 4; ni++) {
            int c = n0 + wn * 64 + ni * 16 + lr;
            float bv = bias[c];
#pragma unroll
            for (int r2 = 0; r2 < 4; r2++) {
                int rg = m0 + wm * 32 + mi * 16 + quad * 4 + r2;
                out[(size_t)rg * N + c] = acc[mi][ni][r2] + bv;
            }
        }
}

// ---------------------------------------------------------------------------
// FALLBACK GEMM (round-3 structure) — only if ws can't hold transposed weights
// ---------------------------------------------------------------------------
__global__ __launch_bounds__(256) void gemm_f32src(
    const void* __restrict__ Araw, const float* __restrict__ Bm,
    const float* __restrict__ bias, float* __restrict__ out,
    short* __restrict__ qw, short* __restrict__ kw, short* __restrict__ vTw,
    int M, int N, int K, int mode)
{
    __shared__ __attribute__((aligned(16))) short As[128 * 32];
    __shared__ __attribute__((aligned(16))) short Bs[128 * 32];

    const int tid  = threadIdx.x;
    const int wave = tid >> 6, lane = tid & 63;
    const int quad = lane >> 4, lr = lane & 15;
    const int wm = wave >> 1, wn = wave & 1;
    const int m0 = blockIdx.y * 128, n0 = blockIdx.x * 128;

    f32x4 acc[4][4];
    const f32x4 zf = {0.f, 0.f, 0.f, 0.f};
#pragma unroll
    for (int mi = 0; mi < 4; mi++)
#pragma unroll
        for (int ni = 0; ni < 4; ni++) acc[mi][ni] = zf;

    for (int k0 = 0; k0 < K; k0 += 32) {
        __syncthreads();
        if (mode == 1) {
            const float* Af = (const float*)Araw;
#pragma unroll
            for (int i = 0; i < 4; i++) {
                int id  = i * 256 + tid;
                int row = id >> 3;
                int kc  = (id & 7) << 2;
                float4 v = *(const float4*)(Af + (size_t)(m0 + row) * K + k0 + kc);
                short* d = &As[row * 32 + kc];
                d[0] = f2b(v.x); d[1] = f2b(v.y); d[2] = f2b(v.z); d[3] = f2b(v.w);
            }
        } else {
            const short* Ah = (const short*)Araw;
#pragma unroll
            for (int i = 0; i < 2; i++) {
                int id  = i * 256 + tid;
                int row = id >> 2;
                int kc  = (id & 3) << 3;
                int rg = m0 + row, b = rg >> 11, t = rg & 2047;
                int c = k0 + kc, h = c >> 6, d = c & 63;
                *(bf16x8*)&As[row * 32 + kc] =
                    *(const bf16x8*)(Ah + ((((size_t)b * Hh + h) * Tt + t) * HD + d));
            }
        }
#pragma unroll
        for (int i = 0; i < 4; i++) {
            int id = i * 256 + tid;
            int kr = id >> 5;
            int nc = (id & 31) << 2;
            float4 v = *(const float4*)(Bm + (size_t)(k0 + kr) * N + n0 + nc);
            Bs[(nc + 0) * 32 + kr] = f2b(v.x);
            Bs[(nc + 1) * 32 + kr] = f2b(v.y);
            Bs[(nc + 2) * 32 + kr] = f2b(v.z);
            Bs[(nc + 3) * 32 + kr] = f2b(v.w);
        }
        __syncthreads();

        bf16x8 af[4], bf[4];
#pragma unroll
        for (int mi = 0; mi < 4; mi++)
            af[mi] = *(bf16x8*)&As[(wm * 64 + mi * 16 + lr) * 32 + quad * 8];
#pragma unroll
        for (int ni = 0; ni < 4; ni++)
            bf[ni] = *(bf16x8*)&Bs[(wn * 64 + ni * 16 + lr) * 32 + quad * 8];
#pragma unroll
        for (int mi = 0; mi < 4; mi++)
#pragma unroll
            for (int ni = 0; ni < 4; ni++)
                acc[mi][ni] = __builtin_amdgcn_mfma_f32_16x16x32_bf16(
                    af[mi], bf[ni], acc[mi][ni], 0, 0, 0);
    }

#pragma unroll
    for (int mi = 0; mi < 4; mi++) {
#pragma unroll
        for (int ni = 0; ni < 4; ni++) {
            int c = n0 + wn * 64 + ni * 16 + lr;
            float bv = bias[c];
#pragma unroll
            for (int r = 0; r < 4; r++) {
                int rg = m0 + wm * 64 + mi * 16 + quad * 4 + r;
                float val = acc[mi][ni][r] + bv;
                if (mode == 1) {
                    int which = c >> 10, cc = c & 1023;
                    int h = cc >> 6, d = cc & 63;
                    int b = rg >> 11, t = rg & 2047;
                    size_t bh = (size_t)b * Hh + h;
                    if (which == 0)      qw[(bh * Tt + t) * HD + d] = f2b(val * QS);
                    else if (which == 1) kw[(bh * Tt + t) * HD + d] = f2b(val);
                    else                 vTw[(bh * HD + d) * Tt + t] = f2b(val);
                } else {
                    out[(size_t)rg * N + c] = val;
                }
            }
        }
    }
}

// ---------------------------------------------------------------------------
// Flash causal attention v10 — load-balanced: 1024 blocks x 256 threads,
// ONE pair (p, 63-p) per block (p = blockIdx>>5, bh = blockIdx&31),
// 4 waves = {row-half wh} x {kt-half kgrp}.
//  - v9's 512x512 grid was statically resident (2 blocks/CU, no refill);
//    block chunk counts span 9..16, so a CU hosting two heavy blocks set
//    the wall (~32 block-chunks vs 24.5 avg). v10 halves the block and
//    doubles the grid: same total block-chunks per CU, but ~2 dispatch
//    rounds with dynamic refill -> wall tracks the average, not the worst
//    pairing. 256-thread barriers also arrive with less skew.
//  - chunk rhythm, staging geometry, kt-split, masking, merge: as v9/v8.
// ---------------------------------------------------------------------------
__global__ __launch_bounds__(256) void attn_kernel(
    short* __restrict__ qw, const short* __restrict__ kw,
    const short* __restrict__ vTw)
{
    __shared__ __attribute__((aligned(16))) short Ks[2][8192]; // 128key x 64d
    __shared__ __attribute__((aligned(16))) short Vs[2][8192]; // 64d x 128key

    const int bh = blockIdx.x & 31;
    const int p  = blockIdx.x >> 5;          // 0..31: this block's pair
    const int tid = threadIdx.x;             // 0..255
    const int wave = tid >> 6, lane = tid & 63;
    const int wh = (wave & 1) * 16, kgrp = wave >> 1;
    const int quad = lane >> 4, lr = lane & 15;

    const int r0m[2] = { p * 32 + wh, (63 - p) * 32 + wh };

    short* qp = qw + (size_t)bh * Tt * HD;
    const short* kp = kw + (size_t)bh * Tt * HD;
    const short* vp = vTw + (size_t)bh * HD * Tt;

    // staging geometry (256 threads, 4 gl16/thread/matrix):
    // K [128 rows x 64 d]: row=id>>3, slot=(id&7)^(row&7)
    // V [64 rows x 128 k]: row=id>>4, slot=(id&15)^(row&15)
    int krow[4], kcol[4], vrow[4], vcol[4];
#pragma unroll
    for (int i = 0; i < 4; i++) {
        int id = i * 256 + tid;
        krow[i] = id >> 3;
        kcol[i] = ((id & 7) ^ (krow[i] & 7)) << 3;
        vrow[i] = id >> 4;
        vcol[i] = ((id & 15) ^ (vrow[i] & 15)) << 3;
    }

    // chunk-invariant read bases (kt folds into ds_read offsets)
    const int kb0b = lr * 64 + ((quad     ^ (lr & 7)) << 3); // + kt*1024
    const int kb1b = lr * 64 + (((4 + quad) ^ (lr & 7)) << 3); // + kt*1024
    const int qh = quad >> 1, ql = quad & 1;
    int vbase[4];
#pragma unroll
    for (int nt = 0; nt < 4; nt++)
        vbase[nt] = (nt * 16 + lr) * 128 + ql * 4;           // + slot*8

    // Q B-fragments (n=lr=q-row, k=quad*8+j=d), q pre-scaled by QS
    bf16x8 aq[2][2];
#pragma unroll
    for (int mt = 0; mt < 2; mt++)
#pragma unroll
        for (int h = 0; h < 2; h++)
            aq[mt][h] = *(const bf16x8*)(qp + (size_t)(r0m[mt] + lr) * HD
                                            + h * 32 + quad * 8);

    const f32x4 zf = {0.f, 0.f, 0.f, 0.f};
    f32x4 o[2][4];
    float lacc[2] = {0.f, 0.f};
#pragma unroll
    for (int mt = 0; mt < 2; mt++)
#pragma unroll
        for (int nt = 0; nt < 4; nt++) o[mt][nt] = zf;

    // prologue: stage chunk 0 into buffer 0
#pragma unroll
    for (int i = 0; i < 4; i++) {
        gl16(kp + (size_t)krow[i] * HD + kcol[i], &Ks[0][(i * 256 + tid) * 8]);
        gl16(vp + (size_t)vrow[i] * Tt + vcol[i], &Vs[0][(i * 256 + tid) * 8]);
    }

    // block loop covers the heavy tile (63-p)
    const int clast = ((63 - p) * 32 + 31) >> 7;
    for (int c = 0; c <= clast; ++c) {
        const int j0 = c << 7;
        const int cur = c & 1;
        __syncthreads();   // buf[cur] loads landed; buf[cur^1] reads done
        if (c < clast) {   // prefetch next chunk, flies during compute
#pragma unroll
            for (int i = 0; i < 4; i++) {
                gl16(kp + (size_t)(j0 + 128 + krow[i]) * HD + kcol[i],
                     &Ks[cur ^ 1][(i * 256 + tid) * 8]);
                gl16(vp + (size_t)vrow[i] * Tt + (j0 + 128) + vcol[i],
                     &Vs[cur ^ 1][(i * 256 + tid) * 8]);
            }
        }
        const short* Kc = &Ks[cur][0];
        const short* Vc = &Vs[cur][0];
        __builtin_amdgcn_s_setprio(1);
#pragma unroll
        for (int k4 = 0; k4 < 4; k4++) {
            const int kt = kgrp * 4 + k4;
            const int k16 = j0 + kt * 16;
            const bool act0 = k16 <= r0m[0] + 15;
            const bool act1 = k16 <= r0m[1] + 15;
            if (!act1 && !act0) break;   // strips monotone in kt
            bf16x8 kb0 = *(const bf16x8*)&Kc[kt * 1024 + kb0b];
            bf16x8 kb1 = *(const bf16x8*)&Kc[kt * 1024 + kb1b];
            const int sl8 = (((kt * 2 + qh) ^ lr) << 3);
            bf16x4 va[4];
#pragma unroll
            for (int nt = 0; nt < 4; nt++)
                va[nt] = *(const bf16x4*)&Vc[vbase[nt] + sl8];
#pragma unroll
            for (int mt = 0; mt < 2; mt++) {
                if (!(mt ? act1 : act0)) continue;
                f32x4 s = __builtin_amdgcn_mfma_f32_16x16x32_bf16(
                    kb0, aq[mt][0], zf, 0, 0, 0);
                s = __builtin_amdgcn_mfma_f32_16x16x32_bf16(
                    kb1, aq[mt][1], s, 0, 0, 0);
                unsigned u[4];
                if (k16 + 15 <= r0m[mt]) {      // interior: no mask (uniform)
#pragma unroll
                    for (int r = 0; r < 4; r++) {
                        float e = __builtin_amdgcn_exp2f(s[r]);
                        u[r] = __builtin_bit_cast(unsigned, e);
                        lacc[mt] += e;
                    }
                } else {                         // diagonal strip: mask
#pragma unroll
                    for (int r = 0; r < 4; r++) {
                        float e = __builtin_amdgcn_exp2f(s[r]);
                        if ((k16 + quad * 4 + r) > (r0m[mt] + lr)) e = 0.f;
                        u[r] = __builtin_bit_cast(unsigned, e);
                        lacc[mt] += e;
                    }
                }
                u32x2 pu = { __builtin_amdgcn_perm(u[1], u[0], 0x07060302u),
                             __builtin_amdgcn_perm(u[3], u[2], 0x07060302u) };
                bf16x4 pt = __builtin_bit_cast(bf16x4, pu);
#pragma unroll
                for (int nt = 0; nt < 4; nt++)
                    o[mt][nt] = __builtin_amdgcn_mfma_f32_16x16x16bf16_1k(
                        va[nt], pt, o[mt][nt], 0, 0, 0);
            }
        }
        __builtin_amdgcn_s_setprio(0);
    }

    // merge kgrp=1 partials into kgrp=0 through LDS (K/V buffers are dead)
    __syncthreads();
    float* po = (float*)&Ks[0][0];          // 2 waves x 64 lanes x 32 f = 16 KB
    float* pl = (float*)&Vs[0][0];
    if (kgrp) {
#pragma unroll
        for (int mt = 0; mt < 2; mt++)
#pragma unroll
            for (int nt = 0; nt < 4; nt++)
                *(f32x4*)&po[((wave & 1) * 64 + lane) * 32 + (mt * 4 + nt) * 4] = o[mt][nt];
        pl[((wave & 1) * 64 + lane) * 2 + 0] = lacc[0];
        pl[((wave & 1) * 64 + lane) * 2 + 1] = lacc[1];
    }
    __syncthreads();
    if (kgrp == 0) {
#pragma unroll
        for (int mt = 0; mt < 2; mt++)
#pragma unroll
            for (int nt = 0; nt < 4; nt++) {
                f32x4 t = *(const f32x4*)&po[((wave & 1) * 64 + lane) * 32 + (mt * 4 + nt) * 4];
#pragma unroll
                for (int r = 0; r < 4; r++) o[mt][nt][r] += t[r];
            }
        lacc[0] += pl[((wave & 1) * 64 + lane) * 2 + 0];
        lacc[1] += pl[((wave & 1) * 64 + lane) * 2 + 1];

        // finish l: sum the 4 key-quarters (quads) per q-row
#pragma unroll
        for (int mt = 0; mt < 2; mt++) {
            lacc[mt] += __shfl_xor(lacc[mt], 16, 64);
            lacc[mt] += __shfl_xor(lacc[mt], 32, 64);
            lacc[mt] = 1.0f / lacc[mt];
        }

        // store: q-row = r0m[mt]+lr, d = nt*16+quad*4..+3
#pragma unroll
        for (int mt = 0; mt < 2; mt++)
#pragma unroll
            for (int nt = 0; nt < 4; nt++) {
                bf16x4 ov;
#pragma unroll
                for (int r = 0; r < 4; r++) ov[r] = f2b(o[mt][nt][r] * lacc[mt]);
                *(bf16x4*)(qp + (size_t)(r0m[mt] + lr) * HD + nt * 16 + quad * 4) = ov;
            }
    }
}

extern "C" void kernel_launch(void* const* d_in, const int* in_sizes, int n_in,
                              void* d_out, int out_size, void* d_ws, size_t ws_size,
                              hipStream_t stream) {
    const float* x      = (const float*)d_in[0];
    const float* w_attn = (const float*)d_in[1];
    const float* b_attn = (const float*)d_in[2];
    const float* w_proj = (const float*)d_in[3];
    const float* b_proj = (const float*)d_in[4];
    float* out = (float*)d_out;

    const size_t per = (size_t)Bb * Hh * Tt * HD;    // 4,194,304 elems (8 MB)
    short* qw  = (short*)d_ws;                        // later holds attn output
    short* kw  = qw + per;
    short* vTw = kw + per;
    const int M = Bb * Tt;                            // 4096

    const size_t need_fast = (3 * per + per + (size_t)3072 * 1024 + (size_t)1024 * 1024) * 2;

    if (ws_size >= need_fast) {
        short* xbf = vTw + per;
        short* wAT = xbf + per;
        short* wPT = wAT + (size_t)3072 * 1024;

        prep_kernel<<<dim3(3072), 256, 0, stream>>>(x, xbf, w_attn, wAT, w_proj, wPT);

        gemm_qkv<<<dim3(768), 256, 0, stream>>>(
            xbf, wAT, b_attn, qw, kw, vTw, M, 3 * Cc, Cc);

        attn_kernel<<<dim3(1024), 256, 0, stream>>>(qw, kw, vTw);

        gemm_proj<<<dim3(Cc / 128, M / 64), 256, 0, stream>>>(
            qw, wPT, b_proj, out, M, Cc, Cc);
    } else {
        gemm_f32src<<<dim3(3 * Cc / 128, M / 128), 256, 0, stream>>>(
            x, w_attn, b_attn, nullptr, qw, kw, vTw, M, 3 * Cc, Cc, 1);

        attn_kernel<<<dim3(1024), 256, 0, stream>>>(qw, kw, vTw);

        gemm_f32src<<<dim3(Cc / 128, M / 128), 256, 0, stream>>>(
            qw, w_proj, b_proj, out, nullptr, nullptr, nullptr, M, Cc, Cc, 2);
    }
}

// Round 10
// 167.267 us; speedup vs baseline: 1.0712x; 1.0712x over previous
//
#include <hip/hip_runtime.h>
#include <hip/hip_bf16.h>

#define Bb 2
#define Tt 2048
#define Cc 1024
#define Hh 16
#define HD 64
// 1/sqrt(64) * log2(e), folded into q at QKV epilogue so attn exp2 needs no mul
#define QS 0.18033688f

typedef __attribute__((ext_vector_type(8))) short bf16x8;
typedef __attribute__((ext_vector_type(4))) short bf16x4;
typedef __attribute__((ext_vector_type(4))) float f32x4;
typedef __attribute__((ext_vector_type(2))) unsigned int u32x2;

__device__ inline short f2b(float f) {
    unsigned int u = __builtin_bit_cast(unsigned int, f);
    unsigned int r = (u + 0x7FFFu + ((u >> 16) & 1u)) >> 16;
    return (short)(unsigned short)r;
}

// async global->LDS, 16B per lane; dst must be wave-uniform base + lane*16
__device__ inline void gl16(const void* g, void* l) {
    __builtin_amdgcn_global_load_lds(
        (const __attribute__((address_space(1))) void*)g,
        (__attribute__((address_space(3))) void*)l, 16, 0, 0);
}

// ---------------------------------------------------------------------------
// Fused pre-pass (single launch):
//   blocks [0,2048):      x fp32 -> bf16
//   blocks [2048,2816):   w_attn [1024,3072] -> wAT [3072][1024] bf16
//   blocks [2816,3072):   w_proj [1024,1024] -> wPT [1024][1024] bf16
// ---------------------------------------------------------------------------
__global__ __launch_bounds__(256) void prep_kernel(
    const float* __restrict__ x, short* __restrict__ xbf,
    const float* __restrict__ wA, short* __restrict__ wAT,
    const float* __restrict__ wP, short* __restrict__ wPT)
{
    const int bx = blockIdx.x, tid = threadIdx.x;
    if (bx < 2048) {
        int i = (bx * 256 + tid) * 8;
        float4 a = *(const float4*)(x + i);
        float4 b = *(const float4*)(x + i + 4);
        bf16x8 v;
        v[0] = f2b(a.x); v[1] = f2b(a.y); v[2] = f2b(a.z); v[3] = f2b(a.w);
        v[4] = f2b(b.x); v[5] = f2b(b.y); v[6] = f2b(b.z); v[7] = f2b(b.w);
        *(bf16x8*)(xbf + i) = v;
        return;
    }
    const float* W; short* WT; int N, t;
    if (bx < 2816) { t = bx - 2048; W = wA; WT = wAT; N = 3072; }
    else           { t = bx - 2816; W = wP; WT = wPT; N = 1024; }
    const int K = 1024;
    int k0 = (t & 15) * 64, n0 = (t >> 4) * 64;
    int nl = tid & 63, kg = tid >> 6;
    int n = n0 + nl;
    short v[16];
#pragma unroll
    for (int i = 0; i < 16; i++)
        v[i] = f2b(W[(size_t)(k0 + kg * 16 + i) * N + n]);
    short* dst = WT + (size_t)n * K + k0 + kg * 16;
    *(bf16x8*)dst = *(bf16x8*)&v[0];
    *(bf16x8*)(dst + 8) = *(bf16x8*)&v[8];
}

#define VM0 asm volatile("s_waitcnt vmcnt(0)" ::: "memory")
#define BARRIER asm volatile("s_barrier" ::: "memory")
#define SCHEDB __builtin_amdgcn_sched_barrier(0)

// ---------------------------------------------------------------------------
// QKV GEMM v6 (round-5/6 winner): 128x128, BK=64, 4 waves, 64 KiB LDS ->
// 2 blocks/CU, grid 768, ONE vmcnt(0)+barrier per K-tile, Gray unique-read,
// XOR-swizzled staging.
// ---------------------------------------------------------------------------
#define STG(nb, kb) { \
    gl16(A + baA0 + (kb), &LB[((nb) << 1) * 4096 + dst8]); \
    gl16(A + baA0 + 32768 + (kb), &LB[((nb) << 1) * 4096 + 2048 + dst8]); \
    gl16(A + baA1 + (kb), &LB[(((nb) << 1) | 1) * 4096 + dst8]); \
    gl16(A + baA1 + 32768 + (kb), &LB[(((nb) << 1) | 1) * 4096 + 2048 + dst8]); \
    gl16(Bt + baB0 + (kb), &LB[16384 + ((nb) << 1) * 4096 + dst8]); \
    gl16(Bt + baB0 + 32768 + (kb), &LB[16384 + ((nb) << 1) * 4096 + 2048 + dst8]); \
    gl16(Bt + baB1 + (kb), &LB[16384 + (((nb) << 1) | 1) * 4096 + dst8]); \
    gl16(Bt + baB1 + 32768 + (kb), &LB[16384 + (((nb) << 1) | 1) * 4096 + 2048 + dst8]); }

#define RD_A(bb, flo) { \
    const short* Ab_ = &LB[(((bb) << 1) | wm) * 4096]; \
    _Pragma("unroll") for (int f_ = 0; f_ < 2; f_++) \
        _Pragma("unroll") for (int kh_ = 0; kh_ < 2; kh_++) \
            af[(flo) + f_][kh_] = *(const bf16x8*)&Ab_[aro[(flo) + f_] + kx[kh_]]; }

#define RD_B(bb, elo) { \
    const short* Bb_ = &LB[16384 + (((bb) << 1) | wn) * 4096]; \
    _Pragma("unroll") for (int e_ = 0; e_ < 2; e_++) \
        _Pragma("unroll") for (int kh_ = 0; kh_ < 2; kh_++) \
            bf[(elo) + e_][kh_] = *(const bf16x8*)&Bb_[bro[(elo) + e_] + kx[kh_]]; }

#define QMM(FH, EH) { \
    __builtin_amdgcn_s_setprio(1); \
    _Pragma("unroll") for (int f_ = 0; f_ < 2; f_++) \
        _Pragma("unroll") for (int e_ = 0; e_ < 2; e_++) \
            _Pragma("unroll") for (int kh_ = 0; kh_ < 2; kh_++) \
                acc[(FH) * 2 + f_][(EH) * 2 + e_] = \
                    __builtin_amdgcn_mfma_f32_16x16x32_bf16( \
                        af[(FH) * 2 + f_][kh_], bf[(EH) * 2 + e_][kh_], \
                        acc[(FH) * 2 + f_][(EH) * 2 + e_], 0, 0, 0); \
    __builtin_amdgcn_s_setprio(0); }

// one K-tile on buffer bb, staging (kb1) into nb; 1 vmcnt + 1 barrier total
#define TILE(bb, nb, kb1) { \
    RD_A(bb, 0); RD_B(bb, 0); \
    STG(nb, kb1); \
    QMM(0, 0); \
    RD_B(bb, 2); QMM(0, 1); \
    RD_A(bb, 2); QMM(1, 1); \
    QMM(1, 0); \
    VM0; BARRIER; SCHEDB; }

#define TILE_LAST(bb) { \
    RD_A(bb, 0); RD_B(bb, 0); \
    QMM(0, 0); \
    RD_B(bb, 2); QMM(0, 1); \
    RD_A(bb, 2); QMM(1, 1); \
    QMM(1, 0); }

__global__ __launch_bounds__(256, 2) void gemm_qkv(
    const short* __restrict__ A, const short* __restrict__ Bt,
    const float* __restrict__ bias,
    short* __restrict__ qw, short* __restrict__ kw, short* __restrict__ vTw,
    int M, int N, int K)
{
    __shared__ __attribute__((aligned(16))) short LB[32768]; // 64 KiB

    const int tid  = threadIdx.x;
    const int wave = tid >> 6, lane = tid & 63;
    const int quad = lane >> 4, lr = lane & 15;
    const int wm = wave >> 1, wn = wave & 1;

    const int bid = blockIdx.x;
    const int sw = (bid & 7) * 96 + (bid >> 3);   // XCD-chunked, bijective (768=8*96)
    const int bx = sw % 24, by = sw / 24;
    const int m0 = by * 128, n0 = bx * 128;

    const int dst8 = tid * 8;
    const int cs = ((tid & 7) ^ ((tid >> 3) & 7)) << 3;
    const size_t baA0 = (size_t)(m0 + (tid >> 3)) * 1024 + cs;
    const size_t baA1 = (size_t)(m0 + 64 + (tid >> 3)) * 1024 + cs;
    const size_t baB0 = (size_t)(n0 + (tid >> 3)) * 1024 + cs;
    const size_t baB1 = (size_t)(n0 + 64 + (tid >> 3)) * 1024 + cs;

    int aro[4], bro[4], kx[2];
#pragma unroll
    for (int f = 0; f < 4; f++) {
        aro[f] = (f * 16 + lr) * 64;
        bro[f] = (f * 16 + lr) * 64;
    }
#pragma unroll
    for (int kh = 0; kh < 2; kh++)
        kx[kh] = (((kh * 4 + quad) ^ (lr & 7)) << 3);

    f32x4 acc[4][4];
    const f32x4 zf = {0.f, 0.f, 0.f, 0.f};
#pragma unroll
    for (int mf = 0; mf < 4; mf++)
#pragma unroll
        for (int nf = 0; nf < 4; nf++) acc[mf][nf] = zf;

    bf16x8 af[4][2], bf[4][2];

    STG(0, 0);
    VM0;
    BARRIER;

    for (int it = 0; it < 7; ++it) {
        TILE(0, 1, (2 * it + 1) << 6);
        TILE(1, 0, (2 * it + 2) << 6);
    }
    TILE(0, 1, 15 << 6);   // tile 14, stages tile 15 -> buf 1
    TILE_LAST(1);          // tile 15

    if (n0 < 2048) {
#pragma unroll
        for (int nf = 0; nf < 4; nf++) {
#pragma unroll
            for (int mf = 0; mf < 4; mf++) {
                int c = n0 + wn * 64 + nf * 16 + lr;
                float bv = bias[c];
#pragma unroll
                for (int r = 0; r < 4; r++) {
                    int rg = m0 + wm * 64 + mf * 16 + quad * 4 + r;
                    float val = acc[mf][nf][r] + bv;
                    int which = c >> 10, cc = c & 1023;
                    int h = cc >> 6, d = cc & 63;
                    int b = rg >> 11, t = rg & 2047;
                    size_t bh = (size_t)b * Hh + h;
                    if (which == 0) qw[(bh * Tt + t) * HD + d] = f2b(val * QS);
                    else            kw[(bh * Tt + t) * HD + d] = f2b(val);
                }
            }
        }
    } else {
        __syncthreads();
#pragma unroll
        for (int nf = 0; nf < 4; nf++) {
            int cl = wn * 64 + nf * 16 + lr;
            float bv = bias[n0 + cl];
#pragma unroll
            for (int mf = 0; mf < 4; mf++)
#pragma unroll
                for (int r = 0; r < 4; r++) {
                    int tl = wm * 64 + mf * 16 + quad * 4 + r;
                    LB[cl * 136 + tl] = f2b(acc[mf][nf][r] + bv);
                }
        }
        __syncthreads();
        const int rl = tid >> 1, half = tid & 1;
        const int cc = (n0 & 1023) + rl;
        const int h = cc >> 6, d = cc & 63;
        const int b = m0 >> 11, tb = (m0 & 2047) + half * 64;
        short* dst = vTw + (((size_t)b * Hh + h) * HD + d) * Tt + tb;
        const short* src = &LB[rl * 136 + half * 64];
#pragma unroll
        for (int jj = 0; jj < 8; jj++)
            *(bf16x8*)(dst + jj * 8) = *(const bf16x8*)(src + jj * 8);
    }
}

// ---------------------------------------------------------------------------
// Proj GEMM v2 (unchanged): 64x128 tile, BK=64, 4 waves, 48 KiB LDS,
// 2 blocks/CU, ONE vmcnt(0)+barrier per K-tile, unique Gray reads.
// ---------------------------------------------------------------------------
#define P_STG(nb, kb) { \
    gl16(A + baA0 + (size_t)(kb) * 2048, &LB[(nb) * 4096 + dst8]); \
    gl16(A + baA1 + (size_t)(kb) * 2048, &LB[(nb) * 4096 + 2048 + dst8]); \
    gl16(Bt + baB0 + (kb), &LB[8192 + (nb) * 8192 + dst8]); \
    gl16(Bt + baB1 + (kb), &LB[8192 + (nb) * 8192 + 2048 + dst8]); \
    gl16(Bt + baB2 + (kb), &LB[8192 + (nb) * 8192 + 4096 + dst8]); \
    gl16(Bt + baB3 + (kb), &LB[8192 + (nb) * 8192 + 6144 + dst8]); }

#define P_RDA(bb) { \
    const short* Ab_ = &LB[(bb) * 4096]; \
    _Pragma("unroll") for (int f_ = 0; f_ < 2; f_++) \
        _Pragma("unroll") for (int kh_ = 0; kh_ < 2; kh_++) \
            af[f_][kh_] = *(const bf16x8*)&Ab_[aro[f_] + kx[kh_]]; }

#define P_RDB(bb, elo) { \
    const short* Bb_ = &LB[8192 + (bb) * 8192]; \
    _Pragma("unroll") for (int e_ = 0; e_ < 2; e_++) \
        _Pragma("unroll") for (int kh_ = 0; kh_ < 2; kh_++) \
            bf[(elo) + e_][kh_] = *(const bf16x8*)&Bb_[bro[(elo) + e_] + kx[kh_]]; }

#define P_QMM(EH) { \
    __builtin_amdgcn_s_setprio(1); \
    _Pragma("unroll") for (int f_ = 0; f_ < 2; f_++) \
        _Pragma("unroll") for (int e_ = 0; e_ < 2; e_++) \
            _Pragma("unroll") for (int kh_ = 0; kh_ < 2; kh_++) \
                acc[f_][(EH) * 2 + e_] = \
                    __builtin_amdgcn_mfma_f32_16x16x32_bf16( \
                        af[f_][kh_], bf[(EH) * 2 + e_][kh_], \
                        acc[f_][(EH) * 2 + e_], 0, 0, 0); \
    __builtin_amdgcn_s_setprio(0); }

#define P_TILE(bb, nb, kb1) { \
    P_RDA(bb); P_RDB(bb, 0); \
    P_STG(nb, kb1); \
    P_QMM(0); \
    P_RDB(bb, 2); P_QMM(1); \
    VM0; BARRIER; SCHEDB; }

#define P_TILE_LAST(bb) { \
    P_RDA(bb); P_RDB(bb, 0); \
    P_QMM(0); \
    P_RDB(bb, 2); P_QMM(1); }

__global__ __launch_bounds__(256, 2) void gemm_proj(
    const short* __restrict__ A, const short* __restrict__ Bt,
    const float* __restrict__ bias, float* __restrict__ out,
    int M, int N, int K)
{
    __shared__ __attribute__((aligned(16))) short LB[24576]; // 48 KiB

    const int tid  = threadIdx.x;
    const int wave = tid >> 6, lane = tid & 63;
    const int quad = lane >> 4, lr = lane & 15;
    const int wm = wave >> 1, wn = wave & 1;
    const int m0 = blockIdx.y * 64, n0 = blockIdx.x * 128;

    const int dst8 = tid * 8;
    const int cs = ((tid & 7) ^ ((tid >> 3) & 7)) << 3;
    size_t baA0, baA1;
    {
        int r0 = m0 + (tid >> 3), r1 = m0 + 32 + (tid >> 3);
        baA0 = (((size_t)(r0 >> 11) * Hh) * Tt + (r0 & 2047)) * HD + cs;
        baA1 = (((size_t)(r1 >> 11) * Hh) * Tt + (r1 & 2047)) * HD + cs;
    }
    const size_t baB0 = (size_t)(n0 + (tid >> 3)) * 1024 + cs;
    const size_t baB1 = (size_t)(n0 + 32 + (tid >> 3)) * 1024 + cs;
    const size_t baB2 = (size_t)(n0 + 64 + (tid >> 3)) * 1024 + cs;
    const size_t baB3 = (size_t)(n0 + 96 + (tid >> 3)) * 1024 + cs;

    int aro[2], bro[4], kx[2];
#pragma unroll
    for (int f = 0; f < 2; f++) aro[f] = (wm * 32 + f * 16 + lr) * 64;
#pragma unroll
    for (int e = 0; e < 4; e++) bro[e] = (wn * 64 + e * 16 + lr) * 64;
#pragma unroll
    for (int kh = 0; kh < 2; kh++)
        kx[kh] = (((kh * 4 + quad) ^ (lr & 7)) << 3);

    f32x4 acc[2][4];
    const f32x4 zf = {0.f, 0.f, 0.f, 0.f};
#pragma unroll
    for (int mi = 0; mi < 2; mi++)
#pragma unroll
        for (int ni = 0; ni < 4; ni++) acc[mi][ni] = zf;

    bf16x8 af[2][2], bf[4][2];

    P_STG(0, 0);
    VM0;
    BARRIER;

    for (int it = 0; it < 7; ++it) {
        P_TILE(0, 1, (2 * it + 1) << 6);
        P_TILE(1, 0, (2 * it + 2) << 6);
    }
    P_TILE(0, 1, 15 << 6);
    P_TILE_LAST(1);

#pragma unroll
    for (int mi = 0; mi < 2; mi++)
#pragma unroll
        for (int ni = 0; ni < 4; ni++) {
            int c = n0 + wn * 64 + ni * 16 + lr;
            float bv = bias[c];
#pragma unroll
            for (int r2 = 0; r2 < 4; r2++) {
                int rg = m0 + wm * 32 + mi * 16 + quad * 4 + r2;
                out[(size_t)rg * N + c] = acc[mi][ni][r2] + bv;
            }
        }
}

// ---------------------------------------------------------------------------
// FALLBACK GEMM (round-3 structure) — only if ws can't hold transposed weights
// ---------------------------------------------------------------------------
__global__ __launch_bounds__(256) void gemm_f32src(
    const void* __restrict__ Araw, const float* __restrict__ Bm,
    const float* __restrict__ bias, float* __restrict__ out,
    short* __restrict__ qw, short* __restrict__ kw, short* __restrict__ vTw,
    int M, int N, int K, int mode)
{
    __shared__ __attribute__((aligned(16))) short As[128 * 32];
    __shared__ __attribute__((aligned(16))) short Bs[128 * 32];

    const int tid  = threadIdx.x;
    const int wave = tid >> 6, lane = tid & 63;
    const int quad = lane >> 4, lr = lane & 15;
    const int wm = wave >> 1, wn = wave & 1;
    const int m0 = blockIdx.y * 128, n0 = blockIdx.x * 128;

    f32x4 acc[4][4];
    const f32x4 zf = {0.f, 0.f, 0.f, 0.f};
#pragma unroll
    for (int mi = 0; mi < 4; mi++)
#pragma unroll
        for (int ni = 0; ni < 4; ni++) acc[mi][ni] = zf;

    for (int k0 = 0; k0 < K; k0 += 32) {
        __syncthreads();
        if (mode == 1) {
            const float* Af = (const float*)Araw;
#pragma unroll
            for (int i = 0; i < 4; i++) {
                int id  = i * 256 + tid;
                int row = id >> 3;
                int kc  = (id & 7) << 2;
                float4 v = *(const float4*)(Af + (size_t)(m0 + row) * K + k0 + kc);
                short* d = &As[row * 32 + kc];
                d[0] = f2b(v.x); d[1] = f2b(v.y); d[2] = f2b(v.z); d[3] = f2b(v.w);
            }
        } else {
            const short* Ah = (const short*)Araw;
#pragma unroll
            for (int i = 0; i < 2; i++) {
                int id  = i * 256 + tid;
                int row = id >> 2;
                int kc  = (id & 3) << 3;
                int rg = m0 + row, b = rg >> 11, t = rg & 2047;
                int c = k0 + kc, h = c >> 6, d = c & 63;
                *(bf16x8*)&As[row * 32 + kc] =
                    *(const bf16x8*)(Ah + ((((size_t)b * Hh + h) * Tt + t) * HD + d));
            }
        }
#pragma unroll
        for (int i = 0; i < 4; i++) {
            int id = i * 256 + tid;
            int kr = id >> 5;
            int nc = (id & 31) << 2;
            float4 v = *(const float4*)(Bm + (size_t)(k0 + kr) * N + n0 + nc);
            Bs[(nc + 0) * 32 + kr] = f2b(v.x);
            Bs[(nc + 1) * 32 + kr] = f2b(v.y);
            Bs[(nc + 2) * 32 + kr] = f2b(v.z);
            Bs[(nc + 3) * 32 + kr] = f2b(v.w);
        }
        __syncthreads();

        bf16x8 af[4], bf[4];
#pragma unroll
        for (int mi = 0; mi < 4; mi++)
            af[mi] = *(bf16x8*)&As[(wm * 64 + mi * 16 + lr) * 32 + quad * 8];
#pragma unroll
        for (int ni = 0; ni < 4; ni++)
            bf[ni] = *(bf16x8*)&Bs[(wn * 64 + ni * 16 + lr) * 32 + quad * 8];
#pragma unroll
        for (int mi = 0; mi < 4; mi++)
#pragma unroll
            for (int ni = 0; ni < 4; ni++)
                acc[mi][ni] = __builtin_amdgcn_mfma_f32_16x16x32_bf16(
                    af[mi], bf[ni], acc[mi][ni], 0, 0, 0);
    }

#pragma unroll
    for (int mi = 0; mi < 4; mi++) {
#pragma unroll
        for (int ni = 0; ni < 4; ni++) {
            int c = n0 + wn * 64 + ni * 16 + lr;
            float bv = bias[c];
#pragma unroll
            for (int r = 0; r < 4; r++) {
                int rg = m0 + wm * 64 + mi * 16 + quad * 4 + r;
                float val = acc[mi][ni][r] + bv;
                if (mode == 1) {
                    int which = c >> 10, cc = c & 1023;
                    int h = cc >> 6, d = cc & 63;
                    int b = rg >> 11, t = rg & 2047;
                    size_t bh = (size_t)b * Hh + h;
                    if (which == 0)      qw[(bh * Tt + t) * HD + d] = f2b(val * QS);
                    else if (which == 1) kw[(bh * Tt + t) * HD + d] = f2b(val);
                    else                 vTw[(bh * HD + d) * Tt + t] = f2b(val);
                } else {
                    out[(size_t)rg * N + c] = val;
                }
            }
        }
    }
}

// ---------------------------------------------------------------------------
// Flash causal attention v9b — REVERT to v9 (round-5/6, part of the measured
// 171.5us best) + interleaved kt ownership.
//  - v10 (1 pair/block) regressed 42->55us: per-chunk compute halved while
//    per-chunk overhead stayed fixed, and grid-wide chunk count doubled.
//    Confirmed: fatter chunks with shared staging win.
//  - v9 structure: 512 blocks x 512 threads; waves 0-3 pair 2g, waves 4-7
//    kt-complement; each staged 128-key chunk shared by 2 pairs.
//  - NEW (only change vs v9): kt = k4*2 + kgrp (interleaved strips) instead
//    of kgrp*4 + k4 (halves). On causal-frontier chunks the active kt prefix
//    now splits evenly across both wave groups instead of idling kgrp=1.
//    Work set identical; break stays monotone in k4.
// ---------------------------------------------------------------------------
__global__ __launch_bounds__(512) void attn_kernel(
    short* __restrict__ qw, const short* __restrict__ kw,
    const short* __restrict__ vTw)
{
    __shared__ __attribute__((aligned(16))) short Ks[2][8192]; // 128key x 64d
    __shared__ __attribute__((aligned(16))) short Vs[2][8192]; // 64d x 128key

    const int bh = blockIdx.x & 31;
    const int g  = blockIdx.x >> 5;          // 0..15
    const int tid = threadIdx.x;             // 0..511
    const int wave = tid >> 6, lane = tid & 63;
    const int wg = wave & 3, kgrp = wave >> 2;   // kgrp: kt-parity owner
    const int quad = lane >> 4, lr = lane & 15;

    const int pA = 2 * g + (wg >> 1);        // this wave's pair
    const int pB = 63 - pA;
    const int wh = (wg & 1) * 16;
    const int r0m[2] = { pA * 32 + wh, pB * 32 + wh };

    short* qp = qw + (size_t)bh * Tt * HD;
    const short* kp = kw + (size_t)bh * Tt * HD;
    const short* vp = vTw + (size_t)bh * HD * Tt;

    // staging geometry (512 threads, 2 gl16/thread/matrix):
    // K [128 rows x 64 d]: row=id>>3, slot=(id&7)^(row&7)
    // V [64 rows x 128 k]: row=id>>4, slot=(id&15)^(row&15)
    int krow[2], kcol[2], vrow[2], vcol[2];
#pragma unroll
    for (int i = 0; i < 2; i++) {
        int id = i * 512 + tid;
        krow[i] = id >> 3;
        kcol[i] = ((id & 7) ^ (krow[i] & 7)) << 3;
        vrow[i] = id >> 4;
        vcol[i] = ((id & 15) ^ (vrow[i] & 15)) << 3;
    }

    // chunk-invariant read bases (kt folds into ds_read offsets)
    const int kb0b = lr * 64 + ((quad     ^ (lr & 7)) << 3); // + kt*1024
    const int kb1b = lr * 64 + (((4 + quad) ^ (lr & 7)) << 3); // + kt*1024
    const int qh = quad >> 1, ql = quad & 1;
    int vbase[4];
#pragma unroll
    for (int nt = 0; nt < 4; nt++)
        vbase[nt] = (nt * 16 + lr) * 128 + ql * 4;           // + slot*8

    // Q B-fragments (n=lr=q-row, k=quad*8+j=d), q pre-scaled by QS
    bf16x8 aq[2][2];
#pragma unroll
    for (int mt = 0; mt < 2; mt++)
#pragma unroll
        for (int h = 0; h < 2; h++)
            aq[mt][h] = *(const bf16x8*)(qp + (size_t)(r0m[mt] + lr) * HD
                                            + h * 32 + quad * 8);

    const f32x4 zf = {0.f, 0.f, 0.f, 0.f};
    f32x4 o[2][4];
    float lacc[2] = {0.f, 0.f};
#pragma unroll
    for (int mt = 0; mt < 2; mt++)
#pragma unroll
        for (int nt = 0; nt < 4; nt++) o[mt][nt] = zf;

    // prologue: stage chunk 0 into buffer 0
#pragma unroll
    for (int i = 0; i < 2; i++) {
        gl16(kp + (size_t)krow[i] * HD + kcol[i], &Ks[0][(i * 512 + tid) * 8]);
        gl16(vp + (size_t)vrow[i] * Tt + vcol[i], &Vs[0][(i * 512 + tid) * 8]);
    }

    // block loop bound covers the heaviest tile in the block (63-2g)
    const int clast = ((63 - 2 * g) * 32 + 31) >> 7;
    for (int c = 0; c <= clast; ++c) {
        const int j0 = c << 7;
        const int cur = c & 1;
        __syncthreads();   // buf[cur] loads landed; buf[cur^1] reads done
        if (c < clast) {   // prefetch next chunk, flies during compute
#pragma unroll
            for (int i = 0; i < 2; i++) {
                gl16(kp + (size_t)(j0 + 128 + krow[i]) * HD + kcol[i],
                     &Ks[cur ^ 1][(i * 512 + tid) * 8]);
                gl16(vp + (size_t)vrow[i] * Tt + (j0 + 128) + vcol[i],
                     &Vs[cur ^ 1][(i * 512 + tid) * 8]);
            }
        }
        const short* Kc = &Ks[cur][0];
        const short* Vc = &Vs[cur][0];
        __builtin_amdgcn_s_setprio(1);
#pragma unroll
        for (int k4 = 0; k4 < 4; k4++) {
            const int kt = k4 * 2 + kgrp;    // interleaved strips (v9b)
            const int k16 = j0 + kt * 16;
            const bool act0 = k16 <= r0m[0] + 15;
            const bool act1 = k16 <= r0m[1] + 15;
            if (!act1 && !act0) break;   // strips monotone in k4
            bf16x8 kb0 = *(const bf16x8*)&Kc[kt * 1024 + kb0b];
            bf16x8 kb1 = *(const bf16x8*)&Kc[kt * 1024 + kb1b];
            const int sl8 = (((kt * 2 + qh) ^ lr) << 3);
            bf16x4 va[4];
#pragma unroll
            for (int nt = 0; nt < 4; nt++)
                va[nt] = *(const bf16x4*)&Vc[vbase[nt] + sl8];
#pragma unroll
            for (int mt = 0; mt < 2; mt++) {
                if (!(mt ? act1 : act0)) continue;
                f32x4 s = __builtin_amdgcn_mfma_f32_16x16x32_bf16(
                    kb0, aq[mt][0], zf, 0, 0, 0);
                s = __builtin_amdgcn_mfma_f32_16x16x32_bf16(
                    kb1, aq[mt][1], s, 0, 0, 0);
                unsigned u[4];
                if (k16 + 15 <= r0m[mt]) {      // interior: no mask (uniform)
#pragma unroll
                    for (int r = 0; r < 4; r++) {
                        float e = __builtin_amdgcn_exp2f(s[r]);
                        u[r] = __builtin_bit_cast(unsigned, e);
                        lacc[mt] += e;
                    }
                } else {                         // diagonal strip: mask
#pragma unroll
                    for (int r = 0; r < 4; r++) {
                        float e = __builtin_amdgcn_exp2f(s[r]);
                        if ((k16 + quad * 4 + r) > (r0m[mt] + lr)) e = 0.f;
                        u[r] = __builtin_bit_cast(unsigned, e);
                        lacc[mt] += e;
                    }
                }
                u32x2 pu = { __builtin_amdgcn_perm(u[1], u[0], 0x07060302u),
                             __builtin_amdgcn_perm(u[3], u[2], 0x07060302u) };
                bf16x4 pt = __builtin_bit_cast(bf16x4, pu);
#pragma unroll
                for (int nt = 0; nt < 4; nt++)
                    o[mt][nt] = __builtin_amdgcn_mfma_f32_16x16x16bf16_1k(
                        va[nt], pt, o[mt][nt], 0, 0, 0);
            }
        }
        __builtin_amdgcn_s_setprio(0);
    }

    // merge kgrp=1 partials into kgrp=0 through LDS (K/V buffers are dead)
    __syncthreads();
    float* po = (float*)&Ks[0][0];          // 32 KB: 4 waves x 64 lanes x 32 f
    float* pl = (float*)&Vs[0][0];
    if (kgrp) {
#pragma unroll
        for (int mt = 0; mt < 2; mt++)
#pragma unroll
            for (int nt = 0; nt < 4; nt++)
                *(f32x4*)&po[(wg * 64 + lane) * 32 + (mt * 4 + nt) * 4] = o[mt][nt];
        pl[(wg * 64 + lane) * 2 + 0] = lacc[0];
        pl[(wg * 64 + lane) * 2 + 1] = lacc[1];
    }
    __syncthreads();
    if (kgrp == 0) {
#pragma unroll
        for (int mt = 0; mt < 2; mt++)
#pragma unroll
            for (int nt = 0; nt < 4; nt++) {
                f32x4 t = *(const f32x4*)&po[(wg * 64 + lane) * 32 + (mt * 4 + nt) * 4];
#pragma unroll
                for (int r = 0; r < 4; r++) o[mt][nt][r] += t[r];
            }
        lacc[0] += pl[(wg * 64 + lane) * 2 + 0];
        lacc[1] += pl[(wg * 64 + lane) * 2 + 1];

        // finish l: sum the 4 key-quarters (quads) per q-row
#pragma unroll
        for (int mt = 0; mt < 2; mt++) {
            lacc[mt] += __shfl_xor(lacc[mt], 16, 64);
            lacc[mt] += __shfl_xor(lacc[mt], 32, 64);
            lacc[mt] = 1.0f / lacc[mt];
        }

        // store: q-row = r0m[mt]+lr, d = nt*16+quad*4..+3
#pragma unroll
        for (int mt = 0; mt < 2; mt++)
#pragma unroll
            for (int nt = 0; nt < 4; nt++) {
                bf16x4 ov;
#pragma unroll
                for (int r = 0; r < 4; r++) ov[r] = f2b(o[mt][nt][r] * lacc[mt]);
                *(bf16x4*)(qp + (size_t)(r0m[mt] + lr) * HD + nt * 16 + quad * 4) = ov;
            }
    }
}

extern "C" void kernel_launch(void* const* d_in, const int* in_sizes, int n_in,
                              void* d_out, int out_size, void* d_ws, size_t ws_size,
                              hipStream_t stream) {
    const float* x      = (const float*)d_in[0];
    const float* w_attn = (const float*)d_in[1];
    const float* b_attn = (const float*)d_in[2];
    const float* w_proj = (const float*)d_in[3];
    const float* b_proj = (const float*)d_in[4];
    float* out = (float*)d_out;

    const size_t per = (size_t)Bb * Hh * Tt * HD;    // 4,194,304 elems (8 MB)
    short* qw  = (short*)d_ws;                        // later holds attn output
    short* kw  = qw + per;
    short* vTw = kw + per;
    const int M = Bb * Tt;                            // 4096

    const size_t need_fast = (3 * per + per + (size_t)3072 * 1024 + (size_t)1024 * 1024) * 2;

    if (ws_size >= need_fast) {
        short* xbf = vTw + per;
        short* wAT = xbf + per;
        short* wPT = wAT + (size_t)3072 * 1024;

        prep_kernel<<<dim3(3072), 256, 0, stream>>>(x, xbf, w_attn, wAT, w_proj, wPT);

        gemm_qkv<<<dim3(768), 256, 0, stream>>>(
            xbf, wAT, b_attn, qw, kw, vTw, M, 3 * Cc, Cc);

        attn_kernel<<<dim3(512), 512, 0, stream>>>(qw, kw, vTw);

        gemm_proj<<<dim3(Cc / 128, M / 64), 256, 0, stream>>>(
            qw, wPT, b_proj, out, M, Cc, Cc);
    } else {
        gemm_f32src<<<dim3(3 * Cc / 128, M / 128), 256, 0, stream>>>(
            x, w_attn, b_attn, nullptr, qw, kw, vTw, M, 3 * Cc, Cc, 1);

        attn_kernel<<<dim3(512), 512, 0, stream>>>(qw, kw, vTw);

        gemm_f32src<<<dim3(Cc / 128, M / 128), 256, 0, stream>>>(
            qw, w_proj, b_proj, out, nullptr, nullptr, nullptr, M, Cc, Cc, 2);
    }
}

// Round 11
// 165.650 us; speedup vs baseline: 1.0816x; 1.0098x over previous
//
#include <hip/hip_runtime.h>
#include <hip/hip_bf16.h>

#define Bb 2
#define Tt 2048
#define Cc 1024
#define Hh 16
#define HD 64
// 1/sqrt(64) * log2(e), folded into q at QKV epilogue so attn exp2 needs no mul
#define QS 0.18033688f

typedef __attribute__((ext_vector_type(8))) short bf16x8;
typedef __attribute__((ext_vector_type(4))) short bf16x4;
typedef __attribute__((ext_vector_type(4))) float f32x4;
typedef __attribute__((ext_vector_type(2))) unsigned int u32x2;

__device__ inline short f2b(float f) {
    unsigned int u = __builtin_bit_cast(unsigned int, f);
    unsigned int r = (u + 0x7FFFu + ((u >> 16) & 1u)) >> 16;
    return (short)(unsigned short)r;
}

// async global->LDS, 16B per lane; dst must be wave-uniform base + lane*16
__device__ inline void gl16(const void* g, void* l) {
    __builtin_amdgcn_global_load_lds(
        (const __attribute__((address_space(1))) void*)g,
        (__attribute__((address_space(3))) void*)l, 16, 0, 0);
}

// ---------------------------------------------------------------------------
// Fused pre-pass (single launch):
//   blocks [0,2048):      x fp32 -> bf16
//   blocks [2048,2816):   w_attn [1024,3072] -> wAT [3072][1024] bf16
//   blocks [2816,3072):   w_proj [1024,1024] -> wPT [1024][1024] bf16
// ---------------------------------------------------------------------------
__global__ __launch_bounds__(256) void prep_kernel(
    const float* __restrict__ x, short* __restrict__ xbf,
    const float* __restrict__ wA, short* __restrict__ wAT,
    const float* __restrict__ wP, short* __restrict__ wPT)
{
    const int bx = blockIdx.x, tid = threadIdx.x;
    if (bx < 2048) {
        int i = (bx * 256 + tid) * 8;
        float4 a = *(const float4*)(x + i);
        float4 b = *(const float4*)(x + i + 4);
        bf16x8 v;
        v[0] = f2b(a.x); v[1] = f2b(a.y); v[2] = f2b(a.z); v[3] = f2b(a.w);
        v[4] = f2b(b.x); v[5] = f2b(b.y); v[6] = f2b(b.z); v[7] = f2b(b.w);
        *(bf16x8*)(xbf + i) = v;
        return;
    }
    const float* W; short* WT; int N, t;
    if (bx < 2816) { t = bx - 2048; W = wA; WT = wAT; N = 3072; }
    else           { t = bx - 2816; W = wP; WT = wPT; N = 1024; }
    const int K = 1024;
    int k0 = (t & 15) * 64, n0 = (t >> 4) * 64;
    int nl = tid & 63, kg = tid >> 6;
    int n = n0 + nl;
    short v[16];
#pragma unroll
    for (int i = 0; i < 16; i++)
        v[i] = f2b(W[(size_t)(k0 + kg * 16 + i) * N + n]);
    short* dst = WT + (size_t)n * K + k0 + kg * 16;
    *(bf16x8*)dst = *(bf16x8*)&v[0];
    *(bf16x8*)(dst + 8) = *(bf16x8*)&v[8];
}

#define VM0 asm volatile("s_waitcnt vmcnt(0)" ::: "memory")
#define BARRIER asm volatile("s_barrier" ::: "memory")
#define SCHEDB __builtin_amdgcn_sched_barrier(0)

// ---------------------------------------------------------------------------
// QKV GEMM v6 (round-5/6 winner): 128x128, BK=64, 4 waves, 64 KiB LDS ->
// 2 blocks/CU, grid 768, ONE vmcnt(0)+barrier per K-tile, Gray unique-read,
// XOR-swizzled staging.
// ---------------------------------------------------------------------------
#define STG(nb, kb) { \
    gl16(A + baA0 + (kb), &LB[((nb) << 1) * 4096 + dst8]); \
    gl16(A + baA0 + 32768 + (kb), &LB[((nb) << 1) * 4096 + 2048 + dst8]); \
    gl16(A + baA1 + (kb), &LB[(((nb) << 1) | 1) * 4096 + dst8]); \
    gl16(A + baA1 + 32768 + (kb), &LB[(((nb) << 1) | 1) * 4096 + 2048 + dst8]); \
    gl16(Bt + baB0 + (kb), &LB[16384 + ((nb) << 1) * 4096 + dst8]); \
    gl16(Bt + baB0 + 32768 + (kb), &LB[16384 + ((nb) << 1) * 4096 + 2048 + dst8]); \
    gl16(Bt + baB1 + (kb), &LB[16384 + (((nb) << 1) | 1) * 4096 + dst8]); \
    gl16(Bt + baB1 + 32768 + (kb), &LB[16384 + (((nb) << 1) | 1) * 4096 + 2048 + dst8]); }

#define RD_A(bb, flo) { \
    const short* Ab_ = &LB[(((bb) << 1) | wm) * 4096]; \
    _Pragma("unroll") for (int f_ = 0; f_ < 2; f_++) \
        _Pragma("unroll") for (int kh_ = 0; kh_ < 2; kh_++) \
            af[(flo) + f_][kh_] = *(const bf16x8*)&Ab_[aro[(flo) + f_] + kx[kh_]]; }

#define RD_B(bb, elo) { \
    const short* Bb_ = &LB[16384 + (((bb) << 1) | wn) * 4096]; \
    _Pragma("unroll") for (int e_ = 0; e_ < 2; e_++) \
        _Pragma("unroll") for (int kh_ = 0; kh_ < 2; kh_++) \
            bf[(elo) + e_][kh_] = *(const bf16x8*)&Bb_[bro[(elo) + e_] + kx[kh_]]; }

#define QMM(FH, EH) { \
    __builtin_amdgcn_s_setprio(1); \
    _Pragma("unroll") for (int f_ = 0; f_ < 2; f_++) \
        _Pragma("unroll") for (int e_ = 0; e_ < 2; e_++) \
            _Pragma("unroll") for (int kh_ = 0; kh_ < 2; kh_++) \
                acc[(FH) * 2 + f_][(EH) * 2 + e_] = \
                    __builtin_amdgcn_mfma_f32_16x16x32_bf16( \
                        af[(FH) * 2 + f_][kh_], bf[(EH) * 2 + e_][kh_], \
                        acc[(FH) * 2 + f_][(EH) * 2 + e_], 0, 0, 0); \
    __builtin_amdgcn_s_setprio(0); }

// one K-tile on buffer bb, staging (kb1) into nb; 1 vmcnt + 1 barrier total
#define TILE(bb, nb, kb1) { \
    RD_A(bb, 0); RD_B(bb, 0); \
    STG(nb, kb1); \
    QMM(0, 0); \
    RD_B(bb, 2); QMM(0, 1); \
    RD_A(bb, 2); QMM(1, 1); \
    QMM(1, 0); \
    VM0; BARRIER; SCHEDB; }

#define TILE_LAST(bb) { \
    RD_A(bb, 0); RD_B(bb, 0); \
    QMM(0, 0); \
    RD_B(bb, 2); QMM(0, 1); \
    RD_A(bb, 2); QMM(1, 1); \
    QMM(1, 0); }

__global__ __launch_bounds__(256, 2) void gemm_qkv(
    const short* __restrict__ A, const short* __restrict__ Bt,
    const float* __restrict__ bias,
    short* __restrict__ qw, short* __restrict__ kw, short* __restrict__ vTw,
    int M, int N, int K)
{
    __shared__ __attribute__((aligned(16))) short LB[32768]; // 64 KiB

    const int tid  = threadIdx.x;
    const int wave = tid >> 6, lane = tid & 63;
    const int quad = lane >> 4, lr = lane & 15;
    const int wm = wave >> 1, wn = wave & 1;

    const int bid = blockIdx.x;
    const int sw = (bid & 7) * 96 + (bid >> 3);   // XCD-chunked, bijective (768=8*96)
    const int bx = sw % 24, by = sw / 24;
    const int m0 = by * 128, n0 = bx * 128;

    const int dst8 = tid * 8;
    const int cs = ((tid & 7) ^ ((tid >> 3) & 7)) << 3;
    const size_t baA0 = (size_t)(m0 + (tid >> 3)) * 1024 + cs;
    const size_t baA1 = (size_t)(m0 + 64 + (tid >> 3)) * 1024 + cs;
    const size_t baB0 = (size_t)(n0 + (tid >> 3)) * 1024 + cs;
    const size_t baB1 = (size_t)(n0 + 64 + (tid >> 3)) * 1024 + cs;

    int aro[4], bro[4], kx[2];
#pragma unroll
    for (int f = 0; f < 4; f++) {
        aro[f] = (f * 16 + lr) * 64;
        bro[f] = (f * 16 + lr) * 64;
    }
#pragma unroll
    for (int kh = 0; kh < 2; kh++)
        kx[kh] = (((kh * 4 + quad) ^ (lr & 7)) << 3);

    f32x4 acc[4][4];
    const f32x4 zf = {0.f, 0.f, 0.f, 0.f};
#pragma unroll
    for (int mf = 0; mf < 4; mf++)
#pragma unroll
        for (int nf = 0; nf < 4; nf++) acc[mf][nf] = zf;

    bf16x8 af[4][2], bf[4][2];

    STG(0, 0);
    VM0;
    BARRIER;

    for (int it = 0; it < 7; ++it) {
        TILE(0, 1, (2 * it + 1) << 6);
        TILE(1, 0, (2 * it + 2) << 6);
    }
    TILE(0, 1, 15 << 6);   // tile 14, stages tile 15 -> buf 1
    TILE_LAST(1);          // tile 15

    if (n0 < 2048) {
#pragma unroll
        for (int nf = 0; nf < 4; nf++) {
#pragma unroll
            for (int mf = 0; mf < 4; mf++) {
                int c = n0 + wn * 64 + nf * 16 + lr;
                float bv = bias[c];
#pragma unroll
                for (int r = 0; r < 4; r++) {
                    int rg = m0 + wm * 64 + mf * 16 + quad * 4 + r;
                    float val = acc[mf][nf][r] + bv;
                    int which = c >> 10, cc = c & 1023;
                    int h = cc >> 6, d = cc & 63;
                    int b = rg >> 11, t = rg & 2047;
                    size_t bh = (size_t)b * Hh + h;
                    if (which == 0) qw[(bh * Tt + t) * HD + d] = f2b(val * QS);
                    else            kw[(bh * Tt + t) * HD + d] = f2b(val);
                }
            }
        }
    } else {
        __syncthreads();
#pragma unroll
        for (int nf = 0; nf < 4; nf++) {
            int cl = wn * 64 + nf * 16 + lr;
            float bv = bias[n0 + cl];
#pragma unroll
            for (int mf = 0; mf < 4; mf++)
#pragma unroll
                for (int r = 0; r < 4; r++) {
                    int tl = wm * 64 + mf * 16 + quad * 4 + r;
                    LB[cl * 136 + tl] = f2b(acc[mf][nf][r] + bv);
                }
        }
        __syncthreads();
        const int rl = tid >> 1, half = tid & 1;
        const int cc = (n0 & 1023) + rl;
        const int h = cc >> 6, d = cc & 63;
        const int b = m0 >> 11, tb = (m0 & 2047) + half * 64;
        short* dst = vTw + (((size_t)b * Hh + h) * HD + d) * Tt + tb;
        const short* src = &LB[rl * 136 + half * 64];
#pragma unroll
        for (int jj = 0; jj < 8; jj++)
            *(bf16x8*)(dst + jj * 8) = *(const bf16x8*)(src + jj * 8);
    }
}

// ---------------------------------------------------------------------------
// Proj GEMM v2 (unchanged): 64x128 tile, BK=64, 4 waves, 48 KiB LDS,
// 2 blocks/CU, ONE vmcnt(0)+barrier per K-tile, unique Gray reads.
// ---------------------------------------------------------------------------
#define P_STG(nb, kb) { \
    gl16(A + baA0 + (size_t)(kb) * 2048, &LB[(nb) * 4096 + dst8]); \
    gl16(A + baA1 + (size_t)(kb) * 2048, &LB[(nb) * 4096 + 2048 + dst8]); \
    gl16(Bt + baB0 + (kb), &LB[8192 + (nb) * 8192 + dst8]); \
    gl16(Bt + baB1 + (kb), &LB[8192 + (nb) * 8192 + 2048 + dst8]); \
    gl16(Bt + baB2 + (kb), &LB[8192 + (nb) * 8192 + 4096 + dst8]); \
    gl16(Bt + baB3 + (kb), &LB[8192 + (nb) * 8192 + 6144 + dst8]); }

#define P_RDA(bb) { \
    const short* Ab_ = &LB[(bb) * 4096]; \
    _Pragma("unroll") for (int f_ = 0; f_ < 2; f_++) \
        _Pragma("unroll") for (int kh_ = 0; kh_ < 2; kh_++) \
            af[f_][kh_] = *(const bf16x8*)&Ab_[aro[f_] + kx[kh_]]; }

#define P_RDB(bb, elo) { \
    const short* Bb_ = &LB[8192 + (bb) * 8192]; \
    _Pragma("unroll") for (int e_ = 0; e_ < 2; e_++) \
        _Pragma("unroll") for (int kh_ = 0; kh_ < 2; kh_++) \
            bf[(elo) + e_][kh_] = *(const bf16x8*)&Bb_[bro[(elo) + e_] + kx[kh_]]; }

#define P_QMM(EH) { \
    __builtin_amdgcn_s_setprio(1); \
    _Pragma("unroll") for (int f_ = 0; f_ < 2; f_++) \
        _Pragma("unroll") for (int e_ = 0; e_ < 2; e_++) \
            _Pragma("unroll") for (int kh_ = 0; kh_ < 2; kh_++) \
                acc[f_][(EH) * 2 + e_] = \
                    __builtin_amdgcn_mfma_f32_16x16x32_bf16( \
                        af[f_][kh_], bf[(EH) * 2 + e_][kh_], \
                        acc[f_][(EH) * 2 + e_], 0, 0, 0); \
    __builtin_amdgcn_s_setprio(0); }

#define P_TILE(bb, nb, kb1) { \
    P_RDA(bb); P_RDB(bb, 0); \
    P_STG(nb, kb1); \
    P_QMM(0); \
    P_RDB(bb, 2); P_QMM(1); \
    VM0; BARRIER; SCHEDB; }

#define P_TILE_LAST(bb) { \
    P_RDA(bb); P_RDB(bb, 0); \
    P_QMM(0); \
    P_RDB(bb, 2); P_QMM(1); }

__global__ __launch_bounds__(256, 2) void gemm_proj(
    const short* __restrict__ A, const short* __restrict__ Bt,
    const float* __restrict__ bias, float* __restrict__ out,
    int M, int N, int K)
{
    __shared__ __attribute__((aligned(16))) short LB[24576]; // 48 KiB

    const int tid  = threadIdx.x;
    const int wave = tid >> 6, lane = tid & 63;
    const int quad = lane >> 4, lr = lane & 15;
    const int wm = wave >> 1, wn = wave & 1;
    const int m0 = blockIdx.y * 64, n0 = blockIdx.x * 128;

    const int dst8 = tid * 8;
    const int cs = ((tid & 7) ^ ((tid >> 3) & 7)) << 3;
    size_t baA0, baA1;
    {
        int r0 = m0 + (tid >> 3), r1 = m0 + 32 + (tid >> 3);
        baA0 = (((size_t)(r0 >> 11) * Hh) * Tt + (r0 & 2047)) * HD + cs;
        baA1 = (((size_t)(r1 >> 11) * Hh) * Tt + (r1 & 2047)) * HD + cs;
    }
    const size_t baB0 = (size_t)(n0 + (tid >> 3)) * 1024 + cs;
    const size_t baB1 = (size_t)(n0 + 32 + (tid >> 3)) * 1024 + cs;
    const size_t baB2 = (size_t)(n0 + 64 + (tid >> 3)) * 1024 + cs;
    const size_t baB3 = (size_t)(n0 + 96 + (tid >> 3)) * 1024 + cs;

    int aro[2], bro[4], kx[2];
#pragma unroll
    for (int f = 0; f < 2; f++) aro[f] = (wm * 32 + f * 16 + lr) * 64;
#pragma unroll
    for (int e = 0; e < 4; e++) bro[e] = (wn * 64 + e * 16 + lr) * 64;
#pragma unroll
    for (int kh = 0; kh < 2; kh++)
        kx[kh] = (((kh * 4 + quad) ^ (lr & 7)) << 3);

    f32x4 acc[2][4];
    const f32x4 zf = {0.f, 0.f, 0.f, 0.f};
#pragma unroll
    for (int mi = 0; mi < 2; mi++)
#pragma unroll
        for (int ni = 0; ni < 4; ni++) acc[mi][ni] = zf;

    bf16x8 af[2][2], bf[4][2];

    P_STG(0, 0);
    VM0;
    BARRIER;

    for (int it = 0; it < 7; ++it) {
        P_TILE(0, 1, (2 * it + 1) << 6);
        P_TILE(1, 0, (2 * it + 2) << 6);
    }
    P_TILE(0, 1, 15 << 6);
    P_TILE_LAST(1);

#pragma unroll
    for (int mi = 0; mi < 2; mi++)
#pragma unroll
        for (int ni = 0; ni < 4; ni++) {
            int c = n0 + wn * 64 + ni * 16 + lr;
            float bv = bias[c];
#pragma unroll
            for (int r2 = 0; r2 < 4; r2++) {
                int rg = m0 + wm * 32 + mi * 16 + quad * 4 + r2;
                out[(size_t)rg * N + c] = acc[mi][ni][r2] + bv;
            }
        }
}

// ---------------------------------------------------------------------------
// FALLBACK GEMM (round-3 structure) — only if ws can't hold transposed weights
// ---------------------------------------------------------------------------
__global__ __launch_bounds__(256) void gemm_f32src(
    const void* __restrict__ Araw, const float* __restrict__ Bm,
    const float* __restrict__ bias, float* __restrict__ out,
    short* __restrict__ qw, short* __restrict__ kw, short* __restrict__ vTw,
    int M, int N, int K, int mode)
{
    __shared__ __attribute__((aligned(16))) short As[128 * 32];
    __shared__ __attribute__((aligned(16))) short Bs[128 * 32];

    const int tid  = threadIdx.x;
    const int wave = tid >> 6, lane = tid & 63;
    const int quad = lane >> 4, lr = lane & 15;
    const int wm = wave >> 1, wn = wave & 1;
    const int m0 = blockIdx.y * 128, n0 = blockIdx.x * 128;

    f32x4 acc[4][4];
    const f32x4 zf = {0.f, 0.f, 0.f, 0.f};
#pragma unroll
    for (int mi = 0; mi < 4; mi++)
#pragma unroll
        for (int ni = 0; ni < 4; ni++) acc[mi][ni] = zf;

    for (int k0 = 0; k0 < K; k0 += 32) {
        __syncthreads();
        if (mode == 1) {
            const float* Af = (const float*)Araw;
#pragma unroll
            for (int i = 0; i < 4; i++) {
                int id  = i * 256 + tid;
                int row = id >> 3;
                int kc  = (id & 7) << 2;
                float4 v = *(const float4*)(Af + (size_t)(m0 + row) * K + k0 + kc);
                short* d = &As[row * 32 + kc];
                d[0] = f2b(v.x); d[1] = f2b(v.y); d[2] = f2b(v.z); d[3] = f2b(v.w);
            }
        } else {
            const short* Ah = (const short*)Araw;
#pragma unroll
            for (int i = 0; i < 2; i++) {
                int id  = i * 256 + tid;
                int row = id >> 2;
                int kc  = (id & 3) << 3;
                int rg = m0 + row, b = rg >> 11, t = rg & 2047;
                int c = k0 + kc, h = c >> 6, d = c & 63;
                *(bf16x8*)&As[row * 32 + kc] =
                    *(const bf16x8*)(Ah + ((((size_t)b * Hh + h) * Tt + t) * HD + d));
            }
        }
#pragma unroll
        for (int i = 0; i < 4; i++) {
            int id = i * 256 + tid;
            int kr = id >> 5;
            int nc = (id & 31) << 2;
            float4 v = *(const float4*)(Bm + (size_t)(k0 + kr) * N + n0 + nc);
            Bs[(nc + 0) * 32 + kr] = f2b(v.x);
            Bs[(nc + 1) * 32 + kr] = f2b(v.y);
            Bs[(nc + 2) * 32 + kr] = f2b(v.z);
            Bs[(nc + 3) * 32 + kr] = f2b(v.w);
        }
        __syncthreads();

        bf16x8 af[4], bf[4];
#pragma unroll
        for (int mi = 0; mi < 4; mi++)
            af[mi] = *(bf16x8*)&As[(wm * 64 + mi * 16 + lr) * 32 + quad * 8];
#pragma unroll
        for (int ni = 0; ni < 4; ni++)
            bf[ni] = *(bf16x8*)&Bs[(wn * 64 + ni * 16 + lr) * 32 + quad * 8];
#pragma unroll
        for (int mi = 0; mi < 4; mi++)
#pragma unroll
            for (int ni = 0; ni < 4; ni++)
                acc[mi][ni] = __builtin_amdgcn_mfma_f32_16x16x32_bf16(
                    af[mi], bf[ni], acc[mi][ni], 0, 0, 0);
    }

#pragma unroll
    for (int mi = 0; mi < 4; mi++) {
#pragma unroll
        for (int ni = 0; ni < 4; ni++) {
            int c = n0 + wn * 64 + ni * 16 + lr;
            float bv = bias[c];
#pragma unroll
            for (int r = 0; r < 4; r++) {
                int rg = m0 + wm * 64 + mi * 16 + quad * 4 + r;
                float val = acc[mi][ni][r] + bv;
                if (mode == 1) {
                    int which = c >> 10, cc = c & 1023;
                    int h = cc >> 6, d = cc & 63;
                    int b = rg >> 11, t = rg & 2047;
                    size_t bh = (size_t)b * Hh + h;
                    if (which == 0)      qw[(bh * Tt + t) * HD + d] = f2b(val * QS);
                    else if (which == 1) kw[(bh * Tt + t) * HD + d] = f2b(val);
                    else                 vTw[(bh * HD + d) * Tt + t] = f2b(val);
                } else {
                    out[(size_t)rg * N + c] = val;
                }
            }
        }
    }
}

// ---------------------------------------------------------------------------
// Flash causal attention v9c — v9b + complementary co-residency pairing.
//  - v9b (interleaved kt) measured as part of the 167.3us best.
//  - NEW (only change): g-remap j=bid>>5, g = j<8 ? j : 23-j. With 8-XCD
//    round-robin dispatch and 512 blocks at 2/CU, co-residents are bid and
//    bid+256, i.e. j and j+8. Old map paired g with g+8 (chunk sums 22..28,
//    wall 28); new map pairs g with 15-g (every sum exactly 25). Bijective
//    over g, bh mapping untouched (same-XCD K/V L2 locality preserved).
//    If the co-residency model is wrong this is provably neutral.
// ---------------------------------------------------------------------------
__global__ __launch_bounds__(512) void attn_kernel(
    short* __restrict__ qw, const short* __restrict__ kw,
    const short* __restrict__ vTw)
{
    __shared__ __attribute__((aligned(16))) short Ks[2][8192]; // 128key x 64d
    __shared__ __attribute__((aligned(16))) short Vs[2][8192]; // 64d x 128key

    const int bh = blockIdx.x & 31;
    const int j  = blockIdx.x >> 5;          // 0..15
    const int g  = (j < 8) ? j : (23 - j);   // pair g with 15-g on a CU
    const int tid = threadIdx.x;             // 0..511
    const int wave = tid >> 6, lane = tid & 63;
    const int wg = wave & 3, kgrp = wave >> 2;   // kgrp: kt-parity owner
    const int quad = lane >> 4, lr = lane & 15;

    const int pA = 2 * g + (wg >> 1);        // this wave's pair
    const int pB = 63 - pA;
    const int wh = (wg & 1) * 16;
    const int r0m[2] = { pA * 32 + wh, pB * 32 + wh };

    short* qp = qw + (size_t)bh * Tt * HD;
    const short* kp = kw + (size_t)bh * Tt * HD;
    const short* vp = vTw + (size_t)bh * HD * Tt;

    // staging geometry (512 threads, 2 gl16/thread/matrix):
    // K [128 rows x 64 d]: row=id>>3, slot=(id&7)^(row&7)
    // V [64 rows x 128 k]: row=id>>4, slot=(id&15)^(row&15)
    int krow[2], kcol[2], vrow[2], vcol[2];
#pragma unroll
    for (int i = 0; i < 2; i++) {
        int id = i * 512 + tid;
        krow[i] = id >> 3;
        kcol[i] = ((id & 7) ^ (krow[i] & 7)) << 3;
        vrow[i] = id >> 4;
        vcol[i] = ((id & 15) ^ (vrow[i] & 15)) << 3;
    }

    // chunk-invariant read bases (kt folds into ds_read offsets)
    const int kb0b = lr * 64 + ((quad     ^ (lr & 7)) << 3); // + kt*1024
    const int kb1b = lr * 64 + (((4 + quad) ^ (lr & 7)) << 3); // + kt*1024
    const int qh = quad >> 1, ql = quad & 1;
    int vbase[4];
#pragma unroll
    for (int nt = 0; nt < 4; nt++)
        vbase[nt] = (nt * 16 + lr) * 128 + ql * 4;           // + slot*8

    // Q B-fragments (n=lr=q-row, k=quad*8+j=d), q pre-scaled by QS
    bf16x8 aq[2][2];
#pragma unroll
    for (int mt = 0; mt < 2; mt++)
#pragma unroll
        for (int h = 0; h < 2; h++)
            aq[mt][h] = *(const bf16x8*)(qp + (size_t)(r0m[mt] + lr) * HD
                                            + h * 32 + quad * 8);

    const f32x4 zf = {0.f, 0.f, 0.f, 0.f};
    f32x4 o[2][4];
    float lacc[2] = {0.f, 0.f};
#pragma unroll
    for (int mt = 0; mt < 2; mt++)
#pragma unroll
        for (int nt = 0; nt < 4; nt++) o[mt][nt] = zf;

    // prologue: stage chunk 0 into buffer 0
#pragma unroll
    for (int i = 0; i < 2; i++) {
        gl16(kp + (size_t)krow[i] * HD + kcol[i], &Ks[0][(i * 512 + tid) * 8]);
        gl16(vp + (size_t)vrow[i] * Tt + vcol[i], &Vs[0][(i * 512 + tid) * 8]);
    }

    // block loop bound covers the heaviest tile in the block (63-2g)
    const int clast = ((63 - 2 * g) * 32 + 31) >> 7;
    for (int c = 0; c <= clast; ++c) {
        const int j0 = c << 7;
        const int cur = c & 1;
        __syncthreads();   // buf[cur] loads landed; buf[cur^1] reads done
        if (c < clast) {   // prefetch next chunk, flies during compute
#pragma unroll
            for (int i = 0; i < 2; i++) {
                gl16(kp + (size_t)(j0 + 128 + krow[i]) * HD + kcol[i],
                     &Ks[cur ^ 1][(i * 512 + tid) * 8]);
                gl16(vp + (size_t)vrow[i] * Tt + (j0 + 128) + vcol[i],
                     &Vs[cur ^ 1][(i * 512 + tid) * 8]);
            }
        }
        const short* Kc = &Ks[cur][0];
        const short* Vc = &Vs[cur][0];
        __builtin_amdgcn_s_setprio(1);
#pragma unroll
        for (int k4 = 0; k4 < 4; k4++) {
            const int kt = k4 * 2 + kgrp;    // interleaved strips (v9b)
            const int k16 = j0 + kt * 16;
            const bool act0 = k16 <= r0m[0] + 15;
            const bool act1 = k16 <= r0m[1] + 15;
            if (!act1 && !act0) break;   // strips monotone in k4
            bf16x8 kb0 = *(const bf16x8*)&Kc[kt * 1024 + kb0b];
            bf16x8 kb1 = *(const bf16x8*)&Kc[kt * 1024 + kb1b];
            const int sl8 = (((kt * 2 + qh) ^ lr) << 3);
            bf16x4 va[4];
#pragma unroll
            for (int nt = 0; nt < 4; nt++)
                va[nt] = *(const bf16x4*)&Vc[vbase[nt] + sl8];
#pragma unroll
            for (int mt = 0; mt < 2; mt++) {
                if (!(mt ? act1 : act0)) continue;
                f32x4 s = __builtin_amdgcn_mfma_f32_16x16x32_bf16(
                    kb0, aq[mt][0], zf, 0, 0, 0);
                s = __builtin_amdgcn_mfma_f32_16x16x32_bf16(
                    kb1, aq[mt][1], s, 0, 0, 0);
                unsigned u[4];
                if (k16 + 15 <= r0m[mt]) {      // interior: no mask (uniform)
#pragma unroll
                    for (int r = 0; r < 4; r++) {
                        float e = __builtin_amdgcn_exp2f(s[r]);
                        u[r] = __builtin_bit_cast(unsigned, e);
                        lacc[mt] += e;
                    }
                } else {                         // diagonal strip: mask
#pragma unroll
                    for (int r = 0; r < 4; r++) {
                        float e = __builtin_amdgcn_exp2f(s[r]);
                        if ((k16 + quad * 4 + r) > (r0m[mt] + lr)) e = 0.f;
                        u[r] = __builtin_bit_cast(unsigned, e);
                        lacc[mt] += e;
                    }
                }
                u32x2 pu = { __builtin_amdgcn_perm(u[1], u[0], 0x07060302u),
                             __builtin_amdgcn_perm(u[3], u[2], 0x07060302u) };
                bf16x4 pt = __builtin_bit_cast(bf16x4, pu);
#pragma unroll
                for (int nt = 0; nt < 4; nt++)
                    o[mt][nt] = __builtin_amdgcn_mfma_f32_16x16x16bf16_1k(
                        va[nt], pt, o[mt][nt], 0, 0, 0);
            }
        }
        __builtin_amdgcn_s_setprio(0);
    }

    // merge kgrp=1 partials into kgrp=0 through LDS (K/V buffers are dead)
    __syncthreads();
    float* po = (float*)&Ks[0][0];          // 32 KB: 4 waves x 64 lanes x 32 f
    float* pl = (float*)&Vs[0][0];
    if (kgrp) {
#pragma unroll
        for (int mt = 0; mt < 2; mt++)
#pragma unroll
            for (int nt = 0; nt < 4; nt++)
                *(f32x4*)&po[(wg * 64 + lane) * 32 + (mt * 4 + nt) * 4] = o[mt][nt];
        pl[(wg * 64 + lane) * 2 + 0] = lacc[0];
        pl[(wg * 64 + lane) * 2 + 1] = lacc[1];
    }
    __syncthreads();
    if (kgrp == 0) {
#pragma unroll
        for (int mt = 0; mt < 2; mt++)
#pragma unroll
            for (int nt = 0; nt < 4; nt++) {
                f32x4 t = *(const f32x4*)&po[(wg * 64 + lane) * 32 + (mt * 4 + nt) * 4];
#pragma unroll
                for (int r = 0; r < 4; r++) o[mt][nt][r] += t[r];
            }
        lacc[0] += pl[(wg * 64 + lane) * 2 + 0];
        lacc[1] += pl[(wg * 64 + lane) * 2 + 1];

        // finish l: sum the 4 key-quarters (quads) per q-row
#pragma unroll
        for (int mt = 0; mt < 2; mt++) {
            lacc[mt] += __shfl_xor(lacc[mt], 16, 64);
            lacc[mt] += __shfl_xor(lacc[mt], 32, 64);
            lacc[mt] = 1.0f / lacc[mt];
        }

        // store: q-row = r0m[mt]+lr, d = nt*16+quad*4..+3
#pragma unroll
        for (int mt = 0; mt < 2; mt++)
#pragma unroll
            for (int nt = 0; nt < 4; nt++) {
                bf16x4 ov;
#pragma unroll
                for (int r = 0; r < 4; r++) ov[r] = f2b(o[mt][nt][r] * lacc[mt]);
                *(bf16x4*)(qp + (size_t)(r0m[mt] + lr) * HD + nt * 16 + quad * 4) = ov;
            }
    }
}

extern "C" void kernel_launch(void* const* d_in, const int* in_sizes, int n_in,
                              void* d_out, int out_size, void* d_ws, size_t ws_size,
                              hipStream_t stream) {
    const float* x      = (const float*)d_in[0];
    const float* w_attn = (const float*)d_in[1];
    const float* b_attn = (const float*)d_in[2];
    const float* w_proj = (const float*)d_in[3];
    const float* b_proj = (const float*)d_in[4];
    float* out = (float*)d_out;

    const size_t per = (size_t)Bb * Hh * Tt * HD;    // 4,194,304 elems (8 MB)
    short* qw  = (short*)d_ws;                        // later holds attn output
    short* kw  = qw + per;
    short* vTw = kw + per;
    const int M = Bb * Tt;                            // 4096

    const size_t need_fast = (3 * per + per + (size_t)3072 * 1024 + (size_t)1024 * 1024) * 2;

    if (ws_size >= need_fast) {
        short* xbf = vTw + per;
        short* wAT = xbf + per;
        short* wPT = wAT + (size_t)3072 * 1024;

        prep_kernel<<<dim3(3072), 256, 0, stream>>>(x, xbf, w_attn, wAT, w_proj, wPT);

        gemm_qkv<<<dim3(768), 256, 0, stream>>>(
            xbf, wAT, b_attn, qw, kw, vTw, M, 3 * Cc, Cc);

        attn_kernel<<<dim3(512), 512, 0, stream>>>(qw, kw, vTw);

        gemm_proj<<<dim3(Cc / 128, M / 64), 256, 0, stream>>>(
            qw, wPT, b_proj, out, M, Cc, Cc);
    } else {
        gemm_f32src<<<dim3(3 * Cc / 128, M / 128), 256, 0, stream>>>(
            x, w_attn, b_attn, nullptr, qw, kw, vTw, M, 3 * Cc, Cc, 1);

        attn_kernel<<<dim3(512), 512, 0, stream>>>(qw, kw, vTw);

        gemm_f32src<<<dim3(Cc / 128, M / 128), 256, 0, stream>>>(
            qw, w_proj, b_proj, out, nullptr, nullptr, nullptr, M, Cc, Cc, 2);
    }
}